// Round 4
// baseline (839.061 us; speedup 1.0000x reference)
//
#include <hip/hip_runtime.h>
#include <hip/hip_bf16.h>

#define N_NODES 50000
#define DIM 128
#define E_EDGES 800000
#define L_LAYERS 3
#define SCAN_BLOCKS 196   // ceil(50000/256)

typedef __attribute__((ext_vector_type(8))) short short8;
typedef __attribute__((ext_vector_type(4))) float f32x4;

__device__ __forceinline__ float bf_to_f(unsigned short u) {
    unsigned int x = ((unsigned int)u) << 16;
    return __builtin_bit_cast(float, x);
}
__device__ __forceinline__ unsigned short f_to_bf(float f) {
    unsigned int x = __builtin_bit_cast(unsigned int, f);
    unsigned int lsb = (x >> 16) & 1u;
    x += 0x7fffu + lsb;   // round-to-nearest-even
    return (unsigned short)(x >> 16);
}
__device__ __forceinline__ void split_bf(float f, unsigned short& hi, unsigned short& lo) {
    hi = f_to_bf(f);
    lo = f_to_bf(f - bf_to_f(hi));
}

// ---- W [L][K][Nn] fp32 -> Wt_hi/Wt_lo [L][Nn][K] bf16 (split) ----
__global__ __launch_bounds__(256) void trans_split_kernel(const float* __restrict__ w,
                                                          unsigned short* __restrict__ wt_hi,
                                                          unsigned short* __restrict__ wt_lo,
                                                          int K, int Nn) {
    int idx = blockIdx.x * 256 + threadIdx.x;
    int per = K * Nn;
    int l = idx / per;
    int r = idx - l * per;
    int k = r / Nn;
    int n = r - k * Nn;
    unsigned short hi, lo;
    split_bf(w[idx], hi, lo);
    size_t o = (size_t)l * per + (size_t)n * K + k;
    wt_hi[o] = hi;
    wt_lo[o] = lo;
}

// ================= CSR build (once per call; graph shared by all layers) ====

__global__ __launch_bounds__(256) void histogram_kernel(const int* __restrict__ ei,
                                                        int* __restrict__ deg) {
    int e = blockIdx.x * 256 + threadIdx.x;
    atomicAdd(&deg[ei[E_EDGES + e]], 1);
}

__global__ __launch_bounds__(256) void scan1_kernel(const int* __restrict__ deg,
                                                    int* __restrict__ rowtmp,
                                                    int* __restrict__ bsum) {
    __shared__ int s[256];
    int t = threadIdx.x;
    int idx = blockIdx.x * 256 + t;
    int v = (idx < N_NODES) ? deg[idx] : 0;
    s[t] = v;
    __syncthreads();
    for (int off = 1; off < 256; off <<= 1) {
        int x = s[t];
        int y = (t >= off) ? s[t - off] : 0;
        __syncthreads();
        s[t] = x + y;
        __syncthreads();
    }
    if (idx < N_NODES) rowtmp[idx] = s[t] - v;
    if (t == 255) bsum[blockIdx.x] = s[255];
}

__global__ __launch_bounds__(256) void scan2_kernel(int* __restrict__ bsum) {
    __shared__ int s[256];
    int t = threadIdx.x;
    int v = (t < SCAN_BLOCKS) ? bsum[t] : 0;
    s[t] = v;
    __syncthreads();
    for (int off = 1; off < 256; off <<= 1) {
        int x = s[t];
        int y = (t >= off) ? s[t - off] : 0;
        __syncthreads();
        s[t] = x + y;
        __syncthreads();
    }
    if (t < SCAN_BLOCKS) bsum[t] = s[t] - v;   // exclusive
}

__global__ __launch_bounds__(256) void scan3_kernel(const int* __restrict__ rowtmp,
                                                    const int* __restrict__ bsum,
                                                    int* __restrict__ row,
                                                    int* __restrict__ cursor) {
    int idx = blockIdx.x * 256 + threadIdx.x;
    if (idx < N_NODES) {
        int rs = rowtmp[idx] + bsum[blockIdx.x];
        row[idx] = rs;
        cursor[idx] = rs;
    }
    if (idx == 0) row[N_NODES] = E_EDGES;
}

__global__ __launch_bounds__(256) void fill_kernel(const int* __restrict__ ei,
                                                   int* __restrict__ cursor,
                                                   int* __restrict__ col) {
    int e = blockIdx.x * 256 + threadIdx.x;
    int dst = ei[E_EDGES + e];
    int pos = atomicAdd(&cursor[dst], 1);
    col[pos] = ei[e];
}

// ---- aggregation (gather): z = (1+eps)*h[i] + sum_j h[j], output split bf16 ----
// one wave per node; lane owns a float2 (128 cols / 64 lanes); 4-wide unroll
__global__ __launch_bounds__(256) void aggregate_kernel(
        const float* __restrict__ h, const int* __restrict__ row,
        const int* __restrict__ col, const float* __restrict__ epsp,
        unsigned short* __restrict__ zh, unsigned short* __restrict__ zl) {
    int wv = threadIdx.x >> 6;
    int lane = threadIdx.x & 63;
    int node = blockIdx.x * 4 + wv;                  // grid = 12500 exactly
    const float2* hp = (const float2*)h;
    size_t base = ((size_t)node * DIM) >> 1;
    float s = 1.0f + epsp[0];
    float2 hv = hp[base + lane];
    float ax = s * hv.x, ay = s * hv.y;
    int e = row[node], e1 = row[node + 1];
    for (; e + 4 <= e1; e += 4) {
        int s0 = col[e], s1 = col[e + 1], s2 = col[e + 2], s3 = col[e + 3];
        float2 v0 = hp[(((size_t)s0 * DIM) >> 1) + lane];
        float2 v1 = hp[(((size_t)s1 * DIM) >> 1) + lane];
        float2 v2 = hp[(((size_t)s2 * DIM) >> 1) + lane];
        float2 v3 = hp[(((size_t)s3 * DIM) >> 1) + lane];
        ax += v0.x + v1.x + v2.x + v3.x;
        ay += v0.y + v1.y + v2.y + v3.y;
    }
    for (; e < e1; ++e) {
        float2 v = hp[(((size_t)col[e] * DIM) >> 1) + lane];
        ax += v.x;
        ay += v.y;
    }
    unsigned short hx, lx, hy, ly;
    split_bf(ax, hx, lx);
    split_bf(ay, hy, ly);
    size_t o = (size_t)node * DIM + lane * 2;
    *(ushort2*)(zh + o) = make_ushort2(hx, hy);
    *(ushort2*)(zl + o) = make_ushort2(lx, ly);
}

// ---- GEMM1: t = relu(bn( z @ W1 + b1 )) ; no LDS, register-direct ----
// grid (782) ; block 256 = 4 waves x 16 rows ; each block: 64 rows x 256 cols
__global__ __launch_bounds__(256) void gemm1_kernel(
        const unsigned short* __restrict__ zh, const unsigned short* __restrict__ zl,
        const unsigned short* __restrict__ w1t_hi, const unsigned short* __restrict__ w1t_lo,
        const float* __restrict__ b1, const float* __restrict__ g1,
        const float* __restrict__ be1, const float* __restrict__ m1,
        const float* __restrict__ v1,
        unsigned short* __restrict__ t_hi, unsigned short* __restrict__ t_lo) {
    const int K = 128;
    const int NN = 256;
    const int wave = threadIdx.x >> 6;
    const int lane = threadIdx.x & 63;
    const int quad = lane >> 4;
    const int l16 = lane & 15;
    const int m0 = blockIdx.x * 64;

    int arow = m0 + wave * 16 + l16;
    int arowc = arow < N_NODES ? arow : N_NODES - 1;
    const unsigned short* zrh = zh + (size_t)arowc * K + quad * 8;
    const unsigned short* zrl = zl + (size_t)arowc * K + quad * 8;
    short8 ah[4], al[4];
    #pragma unroll
    for (int ks = 0; ks < 4; ++ks) {
        ah[ks] = *(const short8*)(zrh + ks * 32);
        al[ks] = *(const short8*)(zrl + ks * 32);
    }

    f32x4 acc[16] = {};
    #pragma unroll
    for (int nt = 0; nt < 16; ++nt) {
        const unsigned short* brh = w1t_hi + (size_t)(nt * 16 + l16) * K + quad * 8;
        const unsigned short* brl = w1t_lo + (size_t)(nt * 16 + l16) * K + quad * 8;
        #pragma unroll
        for (int ks = 0; ks < 4; ++ks) {
            short8 bh = *(const short8*)(brh + ks * 32);
            short8 bl = *(const short8*)(brl + ks * 32);
            acc[nt] = __builtin_amdgcn_mfma_f32_16x16x32_bf16(ah[ks], bh, acc[nt], 0, 0, 0);
            acc[nt] = __builtin_amdgcn_mfma_f32_16x16x32_bf16(ah[ks], bl, acc[nt], 0, 0, 0);
            acc[nt] = __builtin_amdgcn_mfma_f32_16x16x32_bf16(al[ks], bh, acc[nt], 0, 0, 0);
        }
    }

    #pragma unroll
    for (int nt = 0; nt < 16; ++nt) {
        int cg = nt * 16 + l16;
        float bias = b1[cg];
        float scale = g1[cg] * rsqrtf(v1[cg] + 1e-5f);
        float mean = m1[cg];
        float beta = be1[cg];
        #pragma unroll
        for (int r = 0; r < 4; ++r) {
            int rg = m0 + wave * 16 + quad * 4 + r;
            if (rg < N_NODES) {
                float val = (acc[nt][r] + bias - mean) * scale + beta;
                val = fmaxf(val, 0.0f);
                unsigned short hi, lo;
                split_bf(val, hi, lo);
                t_hi[(size_t)rg * NN + cg] = hi;
                t_lo[(size_t)rg * NN + cg] = lo;
            }
        }
    }
}

// ---- GEMM2: h = (t @ W2 + b2) [+ bn+relu] ; no LDS, register-direct ----
// grid (782) ; block 256 = 4 waves x 16 rows ; each block: 64 rows x 128 cols ; K=256
__global__ __launch_bounds__(256) void gemm2_kernel(
        const unsigned short* __restrict__ t_hi, const unsigned short* __restrict__ t_lo,
        const unsigned short* __restrict__ w2t_hi, const unsigned short* __restrict__ w2t_lo,
        const float* __restrict__ b2,
        const float* __restrict__ go, const float* __restrict__ bo,
        const float* __restrict__ mo, const float* __restrict__ vo,
        int do_bn,
        float* __restrict__ hout) {
    const int K = 256;
    const int wave = threadIdx.x >> 6;
    const int lane = threadIdx.x & 63;
    const int quad = lane >> 4;
    const int l16 = lane & 15;
    const int m0 = blockIdx.x * 64;

    int arow = m0 + wave * 16 + l16;
    int arowc = arow < N_NODES ? arow : N_NODES - 1;
    const unsigned short* trh = t_hi + (size_t)arowc * K + quad * 8;
    const unsigned short* trl = t_lo + (size_t)arowc * K + quad * 8;

    f32x4 acc[8] = {};
    #pragma unroll
    for (int ks = 0; ks < 8; ++ks) {
        short8 ah = *(const short8*)(trh + ks * 32);
        short8 al = *(const short8*)(trl + ks * 32);
        #pragma unroll
        for (int nt = 0; nt < 8; ++nt) {
            const unsigned short* brh = w2t_hi + (size_t)(nt * 16 + l16) * K + ks * 32 + quad * 8;
            const unsigned short* brl = w2t_lo + (size_t)(nt * 16 + l16) * K + ks * 32 + quad * 8;
            short8 bh = *(const short8*)brh;
            short8 bl = *(const short8*)brl;
            acc[nt] = __builtin_amdgcn_mfma_f32_16x16x32_bf16(ah, bh, acc[nt], 0, 0, 0);
            acc[nt] = __builtin_amdgcn_mfma_f32_16x16x32_bf16(ah, bl, acc[nt], 0, 0, 0);
            acc[nt] = __builtin_amdgcn_mfma_f32_16x16x32_bf16(al, bh, acc[nt], 0, 0, 0);
        }
    }

    #pragma unroll
    for (int nt = 0; nt < 8; ++nt) {
        int cg = nt * 16 + l16;
        float bias = b2[cg];
        float scale = 1.0f, mean = 0.0f, beta = 0.0f;
        if (do_bn) {
            scale = go[cg] * rsqrtf(vo[cg] + 1e-5f);
            mean = mo[cg];
            beta = bo[cg];
        }
        #pragma unroll
        for (int r = 0; r < 4; ++r) {
            int rg = m0 + wave * 16 + quad * 4 + r;
            if (rg < N_NODES) {
                float val = acc[nt][r] + bias;
                if (do_bn) {
                    val = (val - mean) * scale + beta;
                    val = fmaxf(val, 0.0f);
                }
                hout[(size_t)rg * DIM + cg] = val;
            }
        }
    }
}

// ---- log_softmax over 128 cols, one wave per row, fp32 out ----
__global__ __launch_bounds__(256) void logsoftmax_kernel(
        const float* __restrict__ h, float* __restrict__ out) {
    int wave = threadIdx.x >> 6;
    int lane = threadIdx.x & 63;
    int row = blockIdx.x * 4 + wave;
    const float* hr = h + (size_t)row * DIM;
    float a = hr[lane];
    float b = hr[lane + 64];
    float m = fmaxf(a, b);
    for (int off = 32; off > 0; off >>= 1) m = fmaxf(m, __shfl_xor(m, off, 64));
    float s = expf(a - m) + expf(b - m);
    for (int off = 32; off > 0; off >>= 1) s += __shfl_xor(s, off, 64);
    float ls = logf(s);
    out[(size_t)row * DIM + lane] = a - m - ls;
    out[(size_t)row * DIM + lane + 64] = b - m - ls;
}

extern "C" void kernel_launch(void* const* d_in, const int* in_sizes, int n_in,
                              void* d_out, int out_size, void* d_ws, size_t ws_size,
                              hipStream_t stream) {
    const float* x   = (const float*)d_in[0];
    const int*   ei  = (const int*)d_in[1];
    const float* W1  = (const float*)d_in[2];
    const float* b1  = (const float*)d_in[3];
    const float* g1  = (const float*)d_in[4];
    const float* be1 = (const float*)d_in[5];
    const float* m1  = (const float*)d_in[6];
    const float* v1  = (const float*)d_in[7];
    const float* W2  = (const float*)d_in[8];
    const float* b2  = (const float*)d_in[9];
    const float* eps = (const float*)d_in[10];
    const float* go  = (const float*)d_in[11];
    const float* bo  = (const float*)d_in[12];
    const float* mo  = (const float*)d_in[13];
    const float* vo  = (const float*)d_in[14];

    char* ws = (char*)d_ws;
    float* h = (float*)ws;                      ws += (size_t)N_NODES * DIM * 4;
    unsigned short* zh = (unsigned short*)ws;   ws += (size_t)N_NODES * DIM * 2;
    unsigned short* zl = (unsigned short*)ws;   ws += (size_t)N_NODES * DIM * 2;
    unsigned short* t_hi = (unsigned short*)ws; ws += (size_t)N_NODES * 2 * DIM * 2;
    unsigned short* t_lo = (unsigned short*)ws; ws += (size_t)N_NODES * 2 * DIM * 2;
    unsigned short* w1t_hi = (unsigned short*)ws; ws += (size_t)L_LAYERS * DIM * 2 * DIM * 2;
    unsigned short* w1t_lo = (unsigned short*)ws; ws += (size_t)L_LAYERS * DIM * 2 * DIM * 2;
    unsigned short* w2t_hi = (unsigned short*)ws; ws += (size_t)L_LAYERS * DIM * 2 * DIM * 2;
    unsigned short* w2t_lo = (unsigned short*)ws; ws += (size_t)L_LAYERS * DIM * 2 * DIM * 2;
    int* deg    = (int*)ws; ws += (size_t)N_NODES * 4;
    int* rowtmp = (int*)ws; ws += (size_t)N_NODES * 4;
    int* rowp   = (int*)ws; ws += (size_t)(N_NODES + 1) * 4;
    int* cursor = (int*)ws; ws += (size_t)N_NODES * 4;
    int* bsum   = (int*)ws; ws += 256 * 4;
    int* col    = (int*)ws; ws += (size_t)E_EDGES * 4;

    // ---- CSR build (graph is layer-invariant) ----
    hipMemsetAsync(deg, 0, (size_t)N_NODES * 4, stream);
    histogram_kernel<<<E_EDGES / 256, 256, 0, stream>>>(ei, deg);
    scan1_kernel<<<SCAN_BLOCKS, 256, 0, stream>>>(deg, rowtmp, bsum);
    scan2_kernel<<<1, 256, 0, stream>>>(bsum);
    scan3_kernel<<<SCAN_BLOCKS, 256, 0, stream>>>(rowtmp, bsum, rowp, cursor);
    fill_kernel<<<E_EDGES / 256, 256, 0, stream>>>(ei, cursor, col);

    trans_split_kernel<<<(L_LAYERS * DIM * 2 * DIM) / 256, 256, 0, stream>>>(W1, w1t_hi, w1t_lo, DIM, 2 * DIM);
    trans_split_kernel<<<(L_LAYERS * DIM * 2 * DIM) / 256, 256, 0, stream>>>(W2, w2t_hi, w2t_lo, 2 * DIM, DIM);

    const int mblocks = (N_NODES + 63) / 64;   // 782
    for (int i = 0; i < L_LAYERS; ++i) {
        const float* hsrc = (i == 0) ? x : h;
        aggregate_kernel<<<N_NODES / 4, 256, 0, stream>>>(hsrc, rowp, col, eps + i, zh, zl);
        gemm1_kernel<<<mblocks, 256, 0, stream>>>(zh, zl,
            w1t_hi + (size_t)i * 256 * 128, w1t_lo + (size_t)i * 256 * 128,
            b1 + i * 256, g1 + i * 256, be1 + i * 256, m1 + i * 256, v1 + i * 256,
            t_hi, t_lo);
        int do_bn = (i < L_LAYERS - 1) ? 1 : 0;
        int oi = do_bn ? i : 0;
        gemm2_kernel<<<mblocks, 256, 0, stream>>>(t_hi, t_lo,
            w2t_hi + (size_t)i * 128 * 256, w2t_lo + (size_t)i * 128 * 256,
            b2 + i * 128,
            go + oi * 128, bo + oi * 128, mo + oi * 128, vo + oi * 128,
            do_bn, h);
    }
    logsoftmax_kernel<<<N_NODES / 4, 256, 0, stream>>>(h, (float*)d_out);
}

// Round 5
// 584.365 us; speedup vs baseline: 1.4359x; 1.4359x over previous
//
#include <hip/hip_runtime.h>
#include <hip/hip_bf16.h>

#define N_NODES 50000
#define DIM 128
#define E_EDGES 800000
#define L_LAYERS 3
#define SCAN_BLOCKS 196   // ceil(50000/256)
#define MBLK 1563         // ceil(50000/32); 1563*32 = 50016 rows padded

typedef __attribute__((ext_vector_type(8))) short short8;
typedef __attribute__((ext_vector_type(4))) float f32x4;

__device__ __forceinline__ float bf_to_f(unsigned short u) {
    unsigned int x = ((unsigned int)u) << 16;
    return __builtin_bit_cast(float, x);
}
__device__ __forceinline__ unsigned short f_to_bf(float f) {
    unsigned int x = __builtin_bit_cast(unsigned int, f);
    unsigned int lsb = (x >> 16) & 1u;
    x += 0x7fffu + lsb;   // round-to-nearest-even
    return (unsigned short)(x >> 16);
}
__device__ __forceinline__ void split_bf(float f, unsigned short& hi, unsigned short& lo) {
    hi = f_to_bf(f);
    lo = f_to_bf(f - bf_to_f(hi));
}

// ---- W [L][K][Nn] fp32 -> fragment-contiguous split bf16:
// off = ((((n>>4)*(K/32) + (k>>5))*4 + ((k>>3)&3))*16 + (n&15))*8 + (k&7)
// so a wave's fragment load for (nt,ks) is base + lane*8 (fully coalesced).
__global__ __launch_bounds__(256) void trans_split_kernel(const float* __restrict__ w,
                                                          unsigned short* __restrict__ fh,
                                                          unsigned short* __restrict__ fl,
                                                          int K, int Nn) {
    int idx = blockIdx.x * 256 + threadIdx.x;
    int per = K * Nn;
    int l = idx / per;
    int r = idx - l * per;
    int k = r / Nn;
    int n = r - k * Nn;
    int KS = K >> 5;
    int off = ((((n >> 4) * KS + (k >> 5)) * 4 + ((k >> 3) & 3)) * 16 + (n & 15)) * 8 + (k & 7);
    unsigned short hi, lo;
    split_bf(w[idx], hi, lo);
    fh[(size_t)l * per + off] = hi;
    fl[(size_t)l * per + off] = lo;
}

// ---- fold bias+BN into per-channel scale/shift ----
__global__ __launch_bounds__(256) void prep_params_kernel(
        const float* __restrict__ b1, const float* __restrict__ g1,
        const float* __restrict__ be1, const float* __restrict__ m1,
        const float* __restrict__ v1, const float* __restrict__ b2,
        const float* __restrict__ go, const float* __restrict__ bo,
        const float* __restrict__ mo, const float* __restrict__ vo,
        float* __restrict__ scale1, float* __restrict__ shift1,
        float* __restrict__ scale2, float* __restrict__ shift2) {
    int idx = blockIdx.x * 256 + threadIdx.x;
    if (idx < L_LAYERS * 256) {
        float s = g1[idx] * rsqrtf(v1[idx] + 1e-5f);
        scale1[idx] = s;
        shift1[idx] = (b1[idx] - m1[idx]) * s + be1[idx];
    }
    int idx2 = idx - L_LAYERS * 256;
    if (idx2 >= 0 && idx2 < L_LAYERS * 128) {
        int l = idx2 >> 7;
        if (l < L_LAYERS - 1) {
            float s = go[idx2] * rsqrtf(vo[idx2] + 1e-5f);
            scale2[idx2] = s;
            shift2[idx2] = (b2[idx2] - mo[idx2]) * s + bo[idx2];
        } else {
            scale2[idx2] = 1.0f;
            shift2[idx2] = b2[idx2];
        }
    }
}

// ================= CSR build (once per call; graph shared by all layers) ====

__global__ __launch_bounds__(256) void histogram_kernel(const int* __restrict__ ei,
                                                        int* __restrict__ deg) {
    int e = blockIdx.x * 256 + threadIdx.x;
    atomicAdd(&deg[ei[E_EDGES + e]], 1);
}

__global__ __launch_bounds__(256) void scan1_kernel(const int* __restrict__ deg,
                                                    int* __restrict__ rowtmp,
                                                    int* __restrict__ bsum) {
    __shared__ int s[256];
    int t = threadIdx.x;
    int idx = blockIdx.x * 256 + t;
    int v = (idx < N_NODES) ? deg[idx] : 0;
    s[t] = v;
    __syncthreads();
    for (int off = 1; off < 256; off <<= 1) {
        int x = s[t];
        int y = (t >= off) ? s[t - off] : 0;
        __syncthreads();
        s[t] = x + y;
        __syncthreads();
    }
    if (idx < N_NODES) rowtmp[idx] = s[t] - v;
    if (t == 255) bsum[blockIdx.x] = s[255];
}

__global__ __launch_bounds__(256) void scan2_kernel(int* __restrict__ bsum) {
    __shared__ int s[256];
    int t = threadIdx.x;
    int v = (t < SCAN_BLOCKS) ? bsum[t] : 0;
    s[t] = v;
    __syncthreads();
    for (int off = 1; off < 256; off <<= 1) {
        int x = s[t];
        int y = (t >= off) ? s[t - off] : 0;
        __syncthreads();
        s[t] = x + y;
        __syncthreads();
    }
    if (t < SCAN_BLOCKS) bsum[t] = s[t] - v;   // exclusive
}

__global__ __launch_bounds__(256) void scan3_kernel(const int* __restrict__ rowtmp,
                                                    const int* __restrict__ bsum,
                                                    int* __restrict__ row,
                                                    int* __restrict__ cursor) {
    int idx = blockIdx.x * 256 + threadIdx.x;
    if (idx < N_NODES) {
        int rs = rowtmp[idx] + bsum[blockIdx.x];
        row[idx] = rs;
        cursor[idx] = rs;
    }
    if (idx == 0) row[N_NODES] = E_EDGES;
}

__global__ __launch_bounds__(256) void fill_kernel(const int* __restrict__ ei,
                                                   int* __restrict__ cursor,
                                                   int* __restrict__ col) {
    int e = blockIdx.x * 256 + threadIdx.x;
    int dst = ei[E_EDGES + e];
    int pos = atomicAdd(&cursor[dst], 1);
    col[pos] = ei[e];
}

// ---- aggregation: z = (1+eps)*h[i] + sum_j h[j]; writes z in A-fragment order ----
// one wave per node; lane owns cols 2*lane, 2*lane+1
__global__ __launch_bounds__(256) void aggregate_kernel(
        const float* __restrict__ h, const int* __restrict__ row,
        const int* __restrict__ col, const float* __restrict__ epsp,
        unsigned short* __restrict__ zfh, unsigned short* __restrict__ zfl) {
    int wv = threadIdx.x >> 6;
    int lane = threadIdx.x & 63;
    int node = blockIdx.x * 4 + wv;                  // grid = 12500 exactly
    const float2* hp = (const float2*)h;
    size_t base = ((size_t)node * DIM) >> 1;
    float s = 1.0f + epsp[0];
    float2 hv = hp[base + lane];
    float ax = s * hv.x, ay = s * hv.y;
    int e = row[node], e1 = row[node + 1];
    for (; e + 4 <= e1; e += 4) {
        int s0 = col[e], s1 = col[e + 1], s2 = col[e + 2], s3 = col[e + 3];
        float2 v0 = hp[(((size_t)s0 * DIM) >> 1) + lane];
        float2 v1 = hp[(((size_t)s1 * DIM) >> 1) + lane];
        float2 v2 = hp[(((size_t)s2 * DIM) >> 1) + lane];
        float2 v3 = hp[(((size_t)s3 * DIM) >> 1) + lane];
        ax += v0.x + v1.x + v2.x + v3.x;
        ay += v0.y + v1.y + v2.y + v3.y;
    }
    for (; e < e1; ++e) {
        float2 v = hp[(((size_t)col[e] * DIM) >> 1) + lane];
        ax += v.x;
        ay += v.y;
    }
    unsigned short hx, lx, hy, ly;
    split_bf(ax, hx, lx);
    split_bf(ay, hy, ly);
    // fragment order: k=2*lane(+1): ks=lane>>4, quad=(lane>>2)&3, j=(2*lane)&7
    int mt = node >> 4, r16 = node & 15;
    int ks = lane >> 4, quad = (lane >> 2) & 3, jb = (lane * 2) & 7;
    size_t zo = (((size_t)(mt * 4 + ks)) * 4 + quad) * 128 + r16 * 8 + jb;
    *(ushort2*)(zfh + zo) = make_ushort2(hx, hy);
    *(ushort2*)(zfl + zo) = make_ushort2(lx, ly);
}

// ---- GEMM1: t = relu(bn(z @ W1 + b1)) ; all operands fragment-ordered, no LDS
// grid (1563, 2) ; block 128 = 2 waves x 16 rows ; per wave: 16 rows x 128 cols
__global__ __launch_bounds__(128) void gemm1_kernel(
        const unsigned short* __restrict__ zfh, const unsigned short* __restrict__ zfl,
        const unsigned short* __restrict__ w1fh, const unsigned short* __restrict__ w1fl,
        const float* __restrict__ scale1, const float* __restrict__ shift1,
        unsigned short* __restrict__ tfh, unsigned short* __restrict__ tfl) {
    const int wave = threadIdx.x >> 6;
    const int lane = threadIdx.x & 63;
    const int quad = lane >> 4;
    const int l16 = lane & 15;
    const int R0 = blockIdx.x * 32 + wave * 16;
    const int mt = R0 >> 4;
    const int ntbase = blockIdx.y * 8;

    short8 ah[4], al[4];
    #pragma unroll
    for (int ks = 0; ks < 4; ++ks) {
        size_t o = (((size_t)(mt * 4 + ks)) << 9) + lane * 8;
        ah[ks] = *(const short8*)(zfh + o);
        al[ks] = *(const short8*)(zfl + o);
    }

    f32x4 acc[8] = {};
    #pragma unroll
    for (int nt = 0; nt < 8; ++nt) {
        int ntg = ntbase + nt;
        #pragma unroll
        for (int ks = 0; ks < 4; ++ks) {
            size_t o = (((size_t)(ntg * 4 + ks)) << 9) + lane * 8;
            short8 bh = *(const short8*)(w1fh + o);
            short8 bl = *(const short8*)(w1fl + o);
            acc[nt] = __builtin_amdgcn_mfma_f32_16x16x32_bf16(ah[ks], bh, acc[nt], 0, 0, 0);
            acc[nt] = __builtin_amdgcn_mfma_f32_16x16x32_bf16(ah[ks], bl, acc[nt], 0, 0, 0);
            acc[nt] = __builtin_amdgcn_mfma_f32_16x16x32_bf16(al[ks], bh, acc[nt], 0, 0, 0);
        }
    }

    // epilogue: write t in A-fragment order for gemm2 (K=256 -> KS=8)
    #pragma unroll
    for (int nt = 0; nt < 8; ++nt) {
        int cg = (ntbase + nt) * 16 + l16;
        float sc = scale1[cg];
        float sh = shift1[cg];
        int ksq = (cg >> 5) * 4 + ((cg >> 3) & 3);
        size_t tbase = ((size_t)mt * 32 + ksq) * 128 + (cg & 7);
        #pragma unroll
        for (int r = 0; r < 4; ++r) {
            float val = fmaxf(acc[nt][r] * sc + sh, 0.0f);
            unsigned short hi, lo;
            split_bf(val, hi, lo);
            size_t o = tbase + (quad * 4 + r) * 8;
            tfh[o] = hi;
            tfl[o] = lo;
        }
    }
}

// ---- GEMM2: h = bnrelu?(t @ W2 + b2) ; fragment-ordered operands, no LDS
// grid (1563) ; block 128 = 2 waves x 16 rows ; per wave: 16 rows x 128 cols ; K=256
__global__ __launch_bounds__(128) void gemm2_kernel(
        const unsigned short* __restrict__ tfh, const unsigned short* __restrict__ tfl,
        const unsigned short* __restrict__ w2fh, const unsigned short* __restrict__ w2fl,
        const float* __restrict__ scale2, const float* __restrict__ shift2,
        int do_relu,
        float* __restrict__ hout) {
    const int wave = threadIdx.x >> 6;
    const int lane = threadIdx.x & 63;
    const int quad = lane >> 4;
    const int l16 = lane & 15;
    const int R0 = blockIdx.x * 32 + wave * 16;
    const int mt = R0 >> 4;

    f32x4 acc[8] = {};
    #pragma unroll
    for (int ks = 0; ks < 8; ++ks) {
        size_t oa = (((size_t)(mt * 8 + ks)) << 9) + lane * 8;
        short8 ah = *(const short8*)(tfh + oa);
        short8 al = *(const short8*)(tfl + oa);
        #pragma unroll
        for (int nt = 0; nt < 8; ++nt) {
            size_t ob = (((size_t)(nt * 8 + ks)) << 9) + lane * 8;
            short8 bh = *(const short8*)(w2fh + ob);
            short8 bl = *(const short8*)(w2fl + ob);
            acc[nt] = __builtin_amdgcn_mfma_f32_16x16x32_bf16(ah, bh, acc[nt], 0, 0, 0);
            acc[nt] = __builtin_amdgcn_mfma_f32_16x16x32_bf16(ah, bl, acc[nt], 0, 0, 0);
            acc[nt] = __builtin_amdgcn_mfma_f32_16x16x32_bf16(al, bh, acc[nt], 0, 0, 0);
        }
    }

    #pragma unroll
    for (int nt = 0; nt < 8; ++nt) {
        int cg = nt * 16 + l16;
        float sc = scale2[cg];
        float sh = shift2[cg];
        #pragma unroll
        for (int r = 0; r < 4; ++r) {
            int rg = R0 + quad * 4 + r;
            if (rg < N_NODES) {
                float val = acc[nt][r] * sc + sh;
                if (do_relu) val = fmaxf(val, 0.0f);
                hout[(size_t)rg * DIM + cg] = val;
            }
        }
    }
}

// ---- log_softmax over 128 cols, one wave per row, fp32 out ----
__global__ __launch_bounds__(256) void logsoftmax_kernel(
        const float* __restrict__ h, float* __restrict__ out) {
    int wave = threadIdx.x >> 6;
    int lane = threadIdx.x & 63;
    int row = blockIdx.x * 4 + wave;
    const float* hr = h + (size_t)row * DIM;
    float a = hr[lane];
    float b = hr[lane + 64];
    float m = fmaxf(a, b);
    for (int off = 32; off > 0; off >>= 1) m = fmaxf(m, __shfl_xor(m, off, 64));
    float s = expf(a - m) + expf(b - m);
    for (int off = 32; off > 0; off >>= 1) s += __shfl_xor(s, off, 64);
    float ls = logf(s);
    out[(size_t)row * DIM + lane] = a - m - ls;
    out[(size_t)row * DIM + lane + 64] = b - m - ls;
}

extern "C" void kernel_launch(void* const* d_in, const int* in_sizes, int n_in,
                              void* d_out, int out_size, void* d_ws, size_t ws_size,
                              hipStream_t stream) {
    const float* x   = (const float*)d_in[0];
    const int*   ei  = (const int*)d_in[1];
    const float* W1  = (const float*)d_in[2];
    const float* b1  = (const float*)d_in[3];
    const float* g1  = (const float*)d_in[4];
    const float* be1 = (const float*)d_in[5];
    const float* m1  = (const float*)d_in[6];
    const float* v1  = (const float*)d_in[7];
    const float* W2  = (const float*)d_in[8];
    const float* b2  = (const float*)d_in[9];
    const float* eps = (const float*)d_in[10];
    const float* go  = (const float*)d_in[11];
    const float* bo  = (const float*)d_in[12];
    const float* mo  = (const float*)d_in[13];
    const float* vo  = (const float*)d_in[14];

    const size_t MT = 3126;                     // ceil(50016/16) row tiles
    char* ws = (char*)d_ws;
    float* h = (float*)ws;                      ws += (size_t)N_NODES * DIM * 4;
    unsigned short* zfh = (unsigned short*)ws;  ws += MT * 2048 * 2;   // 16r x 128k per tile
    unsigned short* zfl = (unsigned short*)ws;  ws += MT * 2048 * 2;
    unsigned short* tfh = (unsigned short*)ws;  ws += MT * 4096 * 2;   // 16r x 256k per tile
    unsigned short* tfl = (unsigned short*)ws;  ws += MT * 4096 * 2;
    unsigned short* w1fh = (unsigned short*)ws; ws += (size_t)L_LAYERS * 32768 * 2;
    unsigned short* w1fl = (unsigned short*)ws; ws += (size_t)L_LAYERS * 32768 * 2;
    unsigned short* w2fh = (unsigned short*)ws; ws += (size_t)L_LAYERS * 32768 * 2;
    unsigned short* w2fl = (unsigned short*)ws; ws += (size_t)L_LAYERS * 32768 * 2;
    float* scale1 = (float*)ws; ws += (size_t)L_LAYERS * 256 * 4;
    float* shift1 = (float*)ws; ws += (size_t)L_LAYERS * 256 * 4;
    float* scale2 = (float*)ws; ws += (size_t)L_LAYERS * 128 * 4;
    float* shift2 = (float*)ws; ws += (size_t)L_LAYERS * 128 * 4;
    int* deg    = (int*)ws; ws += (size_t)N_NODES * 4;
    int* rowtmp = (int*)ws; ws += (size_t)N_NODES * 4;
    int* rowp   = (int*)ws; ws += (size_t)(N_NODES + 1) * 4;
    int* cursor = (int*)ws; ws += (size_t)N_NODES * 4;
    int* bsum   = (int*)ws; ws += 256 * 4;
    int* col    = (int*)ws; ws += (size_t)E_EDGES * 4;

    // ---- CSR build (graph is layer-invariant) ----
    hipMemsetAsync(deg, 0, (size_t)N_NODES * 4, stream);
    histogram_kernel<<<E_EDGES / 256, 256, 0, stream>>>(ei, deg);
    scan1_kernel<<<SCAN_BLOCKS, 256, 0, stream>>>(deg, rowtmp, bsum);
    scan2_kernel<<<1, 256, 0, stream>>>(bsum);
    scan3_kernel<<<SCAN_BLOCKS, 256, 0, stream>>>(rowtmp, bsum, rowp, cursor);
    fill_kernel<<<E_EDGES / 256, 256, 0, stream>>>(ei, cursor, col);

    trans_split_kernel<<<(L_LAYERS * DIM * 2 * DIM) / 256, 256, 0, stream>>>(W1, w1fh, w1fl, DIM, 2 * DIM);
    trans_split_kernel<<<(L_LAYERS * DIM * 2 * DIM) / 256, 256, 0, stream>>>(W2, w2fh, w2fl, 2 * DIM, DIM);
    prep_params_kernel<<<5, 256, 0, stream>>>(b1, g1, be1, m1, v1, b2, go, bo, mo, vo,
                                              scale1, shift1, scale2, shift2);

    for (int i = 0; i < L_LAYERS; ++i) {
        const float* hsrc = (i == 0) ? x : h;
        aggregate_kernel<<<N_NODES / 4, 256, 0, stream>>>(hsrc, rowp, col, eps + i, zfh, zfl);
        dim3 g1d(MBLK, 2);
        gemm1_kernel<<<g1d, 128, 0, stream>>>(zfh, zfl,
            w1fh + (size_t)i * 32768, w1fl + (size_t)i * 32768,
            scale1 + i * 256, shift1 + i * 256, tfh, tfl);
        int do_relu = (i < L_LAYERS - 1) ? 1 : 0;
        gemm2_kernel<<<MBLK, 128, 0, stream>>>(tfh, tfl,
            w2fh + (size_t)i * 32768, w2fl + (size_t)i * 32768,
            scale2 + i * 128, shift2 + i * 128, do_relu, h);
    }
    logsoftmax_kernel<<<N_NODES / 4, 256, 0, stream>>>(h, (float*)d_out);
}

// Round 6
// 582.026 us; speedup vs baseline: 1.4416x; 1.0040x over previous
//
#include <hip/hip_runtime.h>
#include <hip/hip_bf16.h>

#define N_NODES 50000
#define DIM 128
#define E_EDGES 800000
#define L_LAYERS 3
#define SCAN_BLOCKS 196   // ceil(50000/256)
#define MBLK 1563         // ceil(50000/32); 1563*32 = 50016 rows padded

typedef __attribute__((ext_vector_type(8))) short short8;
typedef __attribute__((ext_vector_type(4))) float f32x4;

__device__ __forceinline__ float bf_to_f(unsigned short u) {
    unsigned int x = ((unsigned int)u) << 16;
    return __builtin_bit_cast(float, x);
}
__device__ __forceinline__ unsigned short f_to_bf(float f) {
    unsigned int x = __builtin_bit_cast(unsigned int, f);
    unsigned int lsb = (x >> 16) & 1u;
    x += 0x7fffu + lsb;   // round-to-nearest-even
    return (unsigned short)(x >> 16);
}
__device__ __forceinline__ void split_bf(float f, unsigned short& hi, unsigned short& lo) {
    hi = f_to_bf(f);
    lo = f_to_bf(f - bf_to_f(hi));
}

// ---- W [L][K][Nn] fp32 -> fragment-contiguous split bf16 ----
__global__ __launch_bounds__(256) void trans_split_kernel(const float* __restrict__ w,
                                                          unsigned short* __restrict__ fh,
                                                          unsigned short* __restrict__ fl,
                                                          int K, int Nn) {
    int idx = blockIdx.x * 256 + threadIdx.x;
    int per = K * Nn;
    int l = idx / per;
    int r = idx - l * per;
    int k = r / Nn;
    int n = r - k * Nn;
    int KS = K >> 5;
    int off = ((((n >> 4) * KS + (k >> 5)) * 4 + ((k >> 3) & 3)) * 16 + (n & 15)) * 8 + (k & 7);
    unsigned short hi, lo;
    split_bf(w[idx], hi, lo);
    fh[(size_t)l * per + off] = hi;
    fl[(size_t)l * per + off] = lo;
}

// ---- fold bias+BN into per-channel scale/shift ----
__global__ __launch_bounds__(256) void prep_params_kernel(
        const float* __restrict__ b1, const float* __restrict__ g1,
        const float* __restrict__ be1, const float* __restrict__ m1,
        const float* __restrict__ v1, const float* __restrict__ b2,
        const float* __restrict__ go, const float* __restrict__ bo,
        const float* __restrict__ mo, const float* __restrict__ vo,
        float* __restrict__ scale1, float* __restrict__ shift1,
        float* __restrict__ scale2, float* __restrict__ shift2) {
    int idx = blockIdx.x * 256 + threadIdx.x;
    if (idx < L_LAYERS * 256) {
        float s = g1[idx] * rsqrtf(v1[idx] + 1e-5f);
        scale1[idx] = s;
        shift1[idx] = (b1[idx] - m1[idx]) * s + be1[idx];
    }
    int idx2 = idx - L_LAYERS * 256;
    if (idx2 >= 0 && idx2 < L_LAYERS * 128) {
        int l = idx2 >> 7;
        if (l < L_LAYERS - 1) {
            float s = go[idx2] * rsqrtf(vo[idx2] + 1e-5f);
            scale2[idx2] = s;
            shift2[idx2] = (b2[idx2] - mo[idx2]) * s + bo[idx2];
        } else {
            scale2[idx2] = 1.0f;
            shift2[idx2] = b2[idx2];
        }
    }
}

// ================= CSR build (once per call; graph shared by all layers) ====

__global__ __launch_bounds__(256) void histogram_kernel(const int* __restrict__ ei,
                                                        int* __restrict__ deg) {
    int e = blockIdx.x * 256 + threadIdx.x;
    atomicAdd(&deg[ei[E_EDGES + e]], 1);
}

__global__ __launch_bounds__(256) void scan1_kernel(const int* __restrict__ deg,
                                                    int* __restrict__ rowtmp,
                                                    int* __restrict__ bsum) {
    __shared__ int s[256];
    int t = threadIdx.x;
    int idx = blockIdx.x * 256 + t;
    int v = (idx < N_NODES) ? deg[idx] : 0;
    s[t] = v;
    __syncthreads();
    for (int off = 1; off < 256; off <<= 1) {
        int x = s[t];
        int y = (t >= off) ? s[t - off] : 0;
        __syncthreads();
        s[t] = x + y;
        __syncthreads();
    }
    if (idx < N_NODES) rowtmp[idx] = s[t] - v;
    if (t == 255) bsum[blockIdx.x] = s[255];
}

__global__ __launch_bounds__(256) void scan2_kernel(int* __restrict__ bsum) {
    __shared__ int s[256];
    int t = threadIdx.x;
    int v = (t < SCAN_BLOCKS) ? bsum[t] : 0;
    s[t] = v;
    __syncthreads();
    for (int off = 1; off < 256; off <<= 1) {
        int x = s[t];
        int y = (t >= off) ? s[t - off] : 0;
        __syncthreads();
        s[t] = x + y;
        __syncthreads();
    }
    if (t < SCAN_BLOCKS) bsum[t] = s[t] - v;   // exclusive
}

__global__ __launch_bounds__(256) void scan3_kernel(const int* __restrict__ rowtmp,
                                                    const int* __restrict__ bsum,
                                                    int* __restrict__ row,
                                                    int* __restrict__ cursor) {
    int idx = blockIdx.x * 256 + threadIdx.x;
    if (idx < N_NODES) {
        int rs = rowtmp[idx] + bsum[blockIdx.x];
        row[idx] = rs;
        cursor[idx] = rs;
    }
    if (idx == 0) row[N_NODES] = E_EDGES;
}

__global__ __launch_bounds__(256) void fill_kernel(const int* __restrict__ ei,
                                                   int* __restrict__ cursor,
                                                   int* __restrict__ col) {
    int e = blockIdx.x * 256 + threadIdx.x;
    int dst = ei[E_EDGES + e];
    int pos = atomicAdd(&cursor[dst], 1);
    col[pos] = ei[e];
}

// ---- aggregation: z = (1+eps)*h[i] + sum_j h[j]; writes z in A-fragment order ----
// one wave per node; lane owns cols 2*lane, 2*lane+1; 8-wide unrolled gather
__global__ __launch_bounds__(256) void aggregate_kernel(
        const float* __restrict__ h, const int* __restrict__ row,
        const int* __restrict__ col, const float* __restrict__ epsp,
        unsigned short* __restrict__ zfh, unsigned short* __restrict__ zfl) {
    int wv = threadIdx.x >> 6;
    int lane = threadIdx.x & 63;
    int node = blockIdx.x * 4 + wv;                  // grid = 12500 exactly
    const float2* hp = (const float2*)h;
    size_t base = ((size_t)node * DIM) >> 1;
    float s = 1.0f + epsp[0];
    float2 hv = hp[base + lane];
    float ax = s * hv.x, ay = s * hv.y;
    int e = row[node], e1 = row[node + 1];
    for (; e + 8 <= e1; e += 8) {
        int c0 = col[e],     c1 = col[e + 1], c2 = col[e + 2], c3 = col[e + 3];
        int c4 = col[e + 4], c5 = col[e + 5], c6 = col[e + 6], c7 = col[e + 7];
        float2 v0 = hp[(((size_t)c0 * DIM) >> 1) + lane];
        float2 v1 = hp[(((size_t)c1 * DIM) >> 1) + lane];
        float2 v2 = hp[(((size_t)c2 * DIM) >> 1) + lane];
        float2 v3 = hp[(((size_t)c3 * DIM) >> 1) + lane];
        float2 v4 = hp[(((size_t)c4 * DIM) >> 1) + lane];
        float2 v5 = hp[(((size_t)c5 * DIM) >> 1) + lane];
        float2 v6 = hp[(((size_t)c6 * DIM) >> 1) + lane];
        float2 v7 = hp[(((size_t)c7 * DIM) >> 1) + lane];
        ax += ((v0.x + v1.x) + (v2.x + v3.x)) + ((v4.x + v5.x) + (v6.x + v7.x));
        ay += ((v0.y + v1.y) + (v2.y + v3.y)) + ((v4.y + v5.y) + (v6.y + v7.y));
    }
    for (; e < e1; ++e) {
        float2 v = hp[(((size_t)col[e] * DIM) >> 1) + lane];
        ax += v.x;
        ay += v.y;
    }
    unsigned short hx, lx, hy, ly;
    split_bf(ax, hx, lx);
    split_bf(ay, hy, ly);
    int mt = node >> 4, r16 = node & 15;
    int ks = lane >> 4, quad = (lane >> 2) & 3, jb = (lane * 2) & 7;
    size_t zo = (((size_t)(mt * 4 + ks)) * 4 + quad) * 128 + r16 * 8 + jb;
    *(ushort2*)(zfh + zo) = make_ushort2(hx, hy);
    *(ushort2*)(zfl + zo) = make_ushort2(lx, ly);
}

// ---- fused MLP: h' = [bn+relu](relu(bn(z@W1+b1)) @ W2 + b2)  (or log_softmax on last)
// grid (1563) ; block 128 = 2 waves x 16 rows; hidden t lives in wave-private LDS.
// LDS A2-frag layout: plane = ks*4+quadA (32 planes), stride 136 shorts (pad 8);
// off = plane*136 + m*8 + j, m=row&15, k = ks*32 + quadA*8 + j.
__global__ __launch_bounds__(128) void mlp_kernel(
        const unsigned short* __restrict__ zfh, const unsigned short* __restrict__ zfl,
        const unsigned short* __restrict__ w1fh, const unsigned short* __restrict__ w1fl,
        const unsigned short* __restrict__ w2fh, const unsigned short* __restrict__ w2fl,
        const float* __restrict__ scale1, const float* __restrict__ shift1,
        const float* __restrict__ scale2, const float* __restrict__ shift2,
        int last,
        float* __restrict__ hout, float* __restrict__ lsout) {
    __shared__ unsigned short lds[2 * 2 * 4352];   // [wave][hi/lo][32 planes * 136]
    const int wave = threadIdx.x >> 6;
    const int lane = threadIdx.x & 63;
    const int quad = lane >> 4;
    const int l16 = lane & 15;
    const int R0 = blockIdx.x * 32 + wave * 16;
    const int mt = R0 >> 4;
    unsigned short* mh = lds + wave * 8704;
    unsigned short* ml = mh + 4352;

    // ---- phase 1: 16 rows x 256 cols, K=128 ----
    short8 ah[4], al[4];
    #pragma unroll
    for (int ks = 0; ks < 4; ++ks) {
        size_t o = (((size_t)(mt * 4 + ks)) << 9) + lane * 8;
        ah[ks] = *(const short8*)(zfh + o);
        al[ks] = *(const short8*)(zfl + o);
    }
    f32x4 acc[16] = {};
    #pragma unroll
    for (int nt = 0; nt < 16; ++nt) {
        #pragma unroll
        for (int ks = 0; ks < 4; ++ks) {
            size_t o = (((size_t)(nt * 4 + ks)) << 9) + lane * 8;
            short8 bh = *(const short8*)(w1fh + o);
            short8 bl = *(const short8*)(w1fl + o);
            acc[nt] = __builtin_amdgcn_mfma_f32_16x16x32_bf16(ah[nt & 0 | ks], bh, acc[nt], 0, 0, 0);
            acc[nt] = __builtin_amdgcn_mfma_f32_16x16x32_bf16(ah[ks], bl, acc[nt], 0, 0, 0);
            acc[nt] = __builtin_amdgcn_mfma_f32_16x16x32_bf16(al[ks], bh, acc[nt], 0, 0, 0);
        }
    }

    // ---- epilogue 1: relu(bn(.)) -> wave-private LDS in A-fragment order ----
    #pragma unroll
    for (int nt = 0; nt < 16; ++nt) {
        int cg = nt * 16 + l16;
        float sc = scale1[cg];
        float sh = shift1[cg];
        int plane = (cg >> 5) * 4 + ((cg >> 3) & 3);
        int basei = plane * 136 + (cg & 7);
        #pragma unroll
        for (int r = 0; r < 4; ++r) {
            float val = fmaxf(acc[nt][r] * sc + sh, 0.0f);
            unsigned short hi, lo;
            split_bf(val, hi, lo);
            int m = quad * 4 + r;
            mh[basei + m * 8] = hi;
            ml[basei + m * 8] = lo;
        }
    }
    // wave-private: no barrier needed (compiler inserts lgkmcnt waits)

    // ---- phase 2: 16 rows x 128 cols, K=256 ----
    f32x4 acc2[8] = {};
    #pragma unroll
    for (int ks = 0; ks < 8; ++ks) {
        int po = (ks * 4 + quad) * 136 + l16 * 8;
        short8 a2h = *(const short8*)&mh[po];
        short8 a2l = *(const short8*)&ml[po];
        #pragma unroll
        for (int nt = 0; nt < 8; ++nt) {
            size_t ob = (((size_t)(nt * 8 + ks)) << 9) + lane * 8;
            short8 bh = *(const short8*)(w2fh + ob);
            short8 bl = *(const short8*)(w2fl + ob);
            acc2[nt] = __builtin_amdgcn_mfma_f32_16x16x32_bf16(a2h, bh, acc2[nt], 0, 0, 0);
            acc2[nt] = __builtin_amdgcn_mfma_f32_16x16x32_bf16(a2h, bl, acc2[nt], 0, 0, 0);
            acc2[nt] = __builtin_amdgcn_mfma_f32_16x16x32_bf16(a2l, bh, acc2[nt], 0, 0, 0);
        }
    }

    // ---- epilogue 2 ----
    #pragma unroll
    for (int nt = 0; nt < 8; ++nt) {
        int cg = nt * 16 + l16;
        float sc = scale2[cg];
        float sh = shift2[cg];
        #pragma unroll
        for (int r = 0; r < 4; ++r)
            acc2[nt][r] = acc2[nt][r] * sc + sh;
    }
    if (!last) {
        #pragma unroll
        for (int nt = 0; nt < 8; ++nt) {
            int cg = nt * 16 + l16;
            #pragma unroll
            for (int r = 0; r < 4; ++r) {
                int rg = R0 + quad * 4 + r;
                if (rg < N_NODES)
                    hout[(size_t)rg * DIM + cg] = fmaxf(acc2[nt][r], 0.0f);
            }
        }
    } else {
        // fused log_softmax: row = R0 + quad*4 + r; cols spread over l16 x nt
        #pragma unroll
        for (int r = 0; r < 4; ++r) {
            float mx = acc2[0][r];
            #pragma unroll
            for (int nt = 1; nt < 8; ++nt) mx = fmaxf(mx, acc2[nt][r]);
            #pragma unroll
            for (int off = 1; off < 16; off <<= 1) mx = fmaxf(mx, __shfl_xor(mx, off, 64));
            float sum = 0.0f;
            #pragma unroll
            for (int nt = 0; nt < 8; ++nt) sum += expf(acc2[nt][r] - mx);
            #pragma unroll
            for (int off = 1; off < 16; off <<= 1) sum += __shfl_xor(sum, off, 64);
            float ls = mx + logf(sum);
            int rg = R0 + quad * 4 + r;
            if (rg < N_NODES) {
                #pragma unroll
                for (int nt = 0; nt < 8; ++nt)
                    lsout[(size_t)rg * DIM + nt * 16 + l16] = acc2[nt][r] - ls;
            }
        }
    }
}

extern "C" void kernel_launch(void* const* d_in, const int* in_sizes, int n_in,
                              void* d_out, int out_size, void* d_ws, size_t ws_size,
                              hipStream_t stream) {
    const float* x   = (const float*)d_in[0];
    const int*   ei  = (const int*)d_in[1];
    const float* W1  = (const float*)d_in[2];
    const float* b1  = (const float*)d_in[3];
    const float* g1  = (const float*)d_in[4];
    const float* be1 = (const float*)d_in[5];
    const float* m1  = (const float*)d_in[6];
    const float* v1  = (const float*)d_in[7];
    const float* W2  = (const float*)d_in[8];
    const float* b2  = (const float*)d_in[9];
    const float* eps = (const float*)d_in[10];
    const float* go  = (const float*)d_in[11];
    const float* bo  = (const float*)d_in[12];
    const float* mo  = (const float*)d_in[13];
    const float* vo  = (const float*)d_in[14];

    const size_t MT = 3126;                     // ceil(50016/16) row tiles
    char* ws = (char*)d_ws;
    float* h = (float*)ws;                      ws += (size_t)N_NODES * DIM * 4;
    unsigned short* zfh = (unsigned short*)ws;  ws += MT * 2048 * 2;
    unsigned short* zfl = (unsigned short*)ws;  ws += MT * 2048 * 2;
    unsigned short* w1fh = (unsigned short*)ws; ws += (size_t)L_LAYERS * 32768 * 2;
    unsigned short* w1fl = (unsigned short*)ws; ws += (size_t)L_LAYERS * 32768 * 2;
    unsigned short* w2fh = (unsigned short*)ws; ws += (size_t)L_LAYERS * 32768 * 2;
    unsigned short* w2fl = (unsigned short*)ws; ws += (size_t)L_LAYERS * 32768 * 2;
    float* scale1 = (float*)ws; ws += (size_t)L_LAYERS * 256 * 4;
    float* shift1 = (float*)ws; ws += (size_t)L_LAYERS * 256 * 4;
    float* scale2 = (float*)ws; ws += (size_t)L_LAYERS * 128 * 4;
    float* shift2 = (float*)ws; ws += (size_t)L_LAYERS * 128 * 4;
    int* deg    = (int*)ws; ws += (size_t)N_NODES * 4;
    int* rowtmp = (int*)ws; ws += (size_t)N_NODES * 4;
    int* rowp   = (int*)ws; ws += (size_t)(N_NODES + 1) * 4;
    int* cursor = (int*)ws; ws += (size_t)N_NODES * 4;
    int* bsum   = (int*)ws; ws += 256 * 4;
    int* col    = (int*)ws; ws += (size_t)E_EDGES * 4;

    // ---- CSR build (graph is layer-invariant) ----
    hipMemsetAsync(deg, 0, (size_t)N_NODES * 4, stream);
    histogram_kernel<<<E_EDGES / 256, 256, 0, stream>>>(ei, deg);
    scan1_kernel<<<SCAN_BLOCKS, 256, 0, stream>>>(deg, rowtmp, bsum);
    scan2_kernel<<<1, 256, 0, stream>>>(bsum);
    scan3_kernel<<<SCAN_BLOCKS, 256, 0, stream>>>(rowtmp, bsum, rowp, cursor);
    fill_kernel<<<E_EDGES / 256, 256, 0, stream>>>(ei, cursor, col);

    trans_split_kernel<<<(L_LAYERS * DIM * 2 * DIM) / 256, 256, 0, stream>>>(W1, w1fh, w1fl, DIM, 2 * DIM);
    trans_split_kernel<<<(L_LAYERS * DIM * 2 * DIM) / 256, 256, 0, stream>>>(W2, w2fh, w2fl, 2 * DIM, DIM);
    prep_params_kernel<<<5, 256, 0, stream>>>(b1, g1, be1, m1, v1, b2, go, bo, mo, vo,
                                              scale1, shift1, scale2, shift2);

    for (int i = 0; i < L_LAYERS; ++i) {
        const float* hsrc = (i == 0) ? x : h;
        aggregate_kernel<<<N_NODES / 4, 256, 0, stream>>>(hsrc, rowp, col, eps + i, zfh, zfl);
        int last = (i == L_LAYERS - 1) ? 1 : 0;
        mlp_kernel<<<MBLK, 128, 0, stream>>>(zfh, zfl,
            w1fh + (size_t)i * 32768, w1fl + (size_t)i * 32768,
            w2fh + (size_t)i * 32768, w2fl + (size_t)i * 32768,
            scale1 + i * 256, shift1 + i * 256,
            scale2 + i * 128, shift2 + i * 128,
            last, h, (float*)d_out);
    }
}

// Round 7
// 573.605 us; speedup vs baseline: 1.4628x; 1.0147x over previous
//
#include <hip/hip_runtime.h>
#include <hip/hip_bf16.h>

#define N_NODES 50000
#define DIM 128
#define E_EDGES 800000
#define L_LAYERS 3
#define SCAN_BLOCKS 196   // ceil(50000/256)
#define MBLK 1563         // ceil(50000/32); 1563*32 = 50016 rows padded

typedef __attribute__((ext_vector_type(8))) short short8;
typedef __attribute__((ext_vector_type(4))) float f32x4;

__device__ __forceinline__ float bf_to_f(unsigned short u) {
    unsigned int x = ((unsigned int)u) << 16;
    return __builtin_bit_cast(float, x);
}
__device__ __forceinline__ unsigned short f_to_bf(float f) {
    unsigned int x = __builtin_bit_cast(unsigned int, f);
    unsigned int lsb = (x >> 16) & 1u;
    x += 0x7fffu + lsb;   // round-to-nearest-even
    return (unsigned short)(x >> 16);
}
__device__ __forceinline__ void split_bf(float f, unsigned short& hi, unsigned short& lo) {
    hi = f_to_bf(f);
    lo = f_to_bf(f - bf_to_f(hi));
}

// ---- W [L][K][Nn] fp32 -> fragment-contiguous split bf16 ----
__global__ __launch_bounds__(256) void trans_split_kernel(const float* __restrict__ w,
                                                          unsigned short* __restrict__ fh,
                                                          unsigned short* __restrict__ fl,
                                                          int K, int Nn) {
    int idx = blockIdx.x * 256 + threadIdx.x;
    int per = K * Nn;
    int l = idx / per;
    int r = idx - l * per;
    int k = r / Nn;
    int n = r - k * Nn;
    int KS = K >> 5;
    int off = ((((n >> 4) * KS + (k >> 5)) * 4 + ((k >> 3) & 3)) * 16 + (n & 15)) * 8 + (k & 7);
    unsigned short hi, lo;
    split_bf(w[idx], hi, lo);
    fh[(size_t)l * per + off] = hi;
    fl[(size_t)l * per + off] = lo;
}

// ---- fold bias+BN into per-channel scale/shift ----
__global__ __launch_bounds__(256) void prep_params_kernel(
        const float* __restrict__ b1, const float* __restrict__ g1,
        const float* __restrict__ be1, const float* __restrict__ m1,
        const float* __restrict__ v1, const float* __restrict__ b2,
        const float* __restrict__ go, const float* __restrict__ bo,
        const float* __restrict__ mo, const float* __restrict__ vo,
        float* __restrict__ scale1, float* __restrict__ shift1,
        float* __restrict__ scale2, float* __restrict__ shift2) {
    int idx = blockIdx.x * 256 + threadIdx.x;
    if (idx < L_LAYERS * 256) {
        float s = g1[idx] * rsqrtf(v1[idx] + 1e-5f);
        scale1[idx] = s;
        shift1[idx] = (b1[idx] - m1[idx]) * s + be1[idx];
    }
    int idx2 = idx - L_LAYERS * 256;
    if (idx2 >= 0 && idx2 < L_LAYERS * 128) {
        int l = idx2 >> 7;
        if (l < L_LAYERS - 1) {
            float s = go[idx2] * rsqrtf(vo[idx2] + 1e-5f);
            scale2[idx2] = s;
            shift2[idx2] = (b2[idx2] - mo[idx2]) * s + bo[idx2];
        } else {
            scale2[idx2] = 1.0f;
            shift2[idx2] = b2[idx2];
        }
    }
}

// ================= CSR build (once per call; graph shared by all layers) ====

__global__ __launch_bounds__(256) void histogram_kernel(const int* __restrict__ ei,
                                                        int* __restrict__ deg) {
    int e = blockIdx.x * 256 + threadIdx.x;
    atomicAdd(&deg[ei[E_EDGES + e]], 1);
}

__global__ __launch_bounds__(256) void scan1_kernel(const int* __restrict__ deg,
                                                    int* __restrict__ rowtmp,
                                                    int* __restrict__ bsum) {
    __shared__ int s[256];
    int t = threadIdx.x;
    int idx = blockIdx.x * 256 + t;
    int v = (idx < N_NODES) ? deg[idx] : 0;
    s[t] = v;
    __syncthreads();
    for (int off = 1; off < 256; off <<= 1) {
        int x = s[t];
        int y = (t >= off) ? s[t - off] : 0;
        __syncthreads();
        s[t] = x + y;
        __syncthreads();
    }
    if (idx < N_NODES) rowtmp[idx] = s[t] - v;
    if (t == 255) bsum[blockIdx.x] = s[255];
}

__global__ __launch_bounds__(256) void scan2_kernel(int* __restrict__ bsum) {
    __shared__ int s[256];
    int t = threadIdx.x;
    int v = (t < SCAN_BLOCKS) ? bsum[t] : 0;
    s[t] = v;
    __syncthreads();
    for (int off = 1; off < 256; off <<= 1) {
        int x = s[t];
        int y = (t >= off) ? s[t - off] : 0;
        __syncthreads();
        s[t] = x + y;
        __syncthreads();
    }
    if (t < SCAN_BLOCKS) bsum[t] = s[t] - v;   // exclusive
}

__global__ __launch_bounds__(256) void scan3_kernel(const int* __restrict__ rowtmp,
                                                    const int* __restrict__ bsum,
                                                    int* __restrict__ row,
                                                    int* __restrict__ cursor) {
    int idx = blockIdx.x * 256 + threadIdx.x;
    if (idx < N_NODES) {
        int rs = rowtmp[idx] + bsum[blockIdx.x];
        row[idx] = rs;
        cursor[idx] = rs;
    }
    if (idx == 0) row[N_NODES] = E_EDGES;
}

__global__ __launch_bounds__(256) void fill_kernel(const int* __restrict__ ei,
                                                   int* __restrict__ cursor,
                                                   int* __restrict__ col) {
    int e = blockIdx.x * 256 + threadIdx.x;
    int dst = ei[E_EDGES + e];
    int pos = atomicAdd(&cursor[dst], 1);
    col[pos] = ei[e];
}

// ---- aggregation: z = (1+eps)*h[i] + sum_j h[j]; writes z in A-fragment order ----
__global__ __launch_bounds__(256) void aggregate_kernel(
        const float* __restrict__ h, const int* __restrict__ row,
        const int* __restrict__ col, const float* __restrict__ epsp,
        unsigned short* __restrict__ zfh, unsigned short* __restrict__ zfl) {
    int wv = threadIdx.x >> 6;
    int lane = threadIdx.x & 63;
    int node = blockIdx.x * 4 + wv;                  // grid = 12500 exactly
    const float2* hp = (const float2*)h;
    size_t base = ((size_t)node * DIM) >> 1;
    float s = 1.0f + epsp[0];
    float2 hv = hp[base + lane];
    float ax = s * hv.x, ay = s * hv.y;
    int e = row[node], e1 = row[node + 1];
    for (; e + 8 <= e1; e += 8) {
        int c0 = col[e],     c1 = col[e + 1], c2 = col[e + 2], c3 = col[e + 3];
        int c4 = col[e + 4], c5 = col[e + 5], c6 = col[e + 6], c7 = col[e + 7];
        float2 v0 = hp[(((size_t)c0 * DIM) >> 1) + lane];
        float2 v1 = hp[(((size_t)c1 * DIM) >> 1) + lane];
        float2 v2 = hp[(((size_t)c2 * DIM) >> 1) + lane];
        float2 v3 = hp[(((size_t)c3 * DIM) >> 1) + lane];
        float2 v4 = hp[(((size_t)c4 * DIM) >> 1) + lane];
        float2 v5 = hp[(((size_t)c5 * DIM) >> 1) + lane];
        float2 v6 = hp[(((size_t)c6 * DIM) >> 1) + lane];
        float2 v7 = hp[(((size_t)c7 * DIM) >> 1) + lane];
        ax += ((v0.x + v1.x) + (v2.x + v3.x)) + ((v4.x + v5.x) + (v6.x + v7.x));
        ay += ((v0.y + v1.y) + (v2.y + v3.y)) + ((v4.y + v5.y) + (v6.y + v7.y));
    }
    for (; e < e1; ++e) {
        float2 v = hp[(((size_t)col[e] * DIM) >> 1) + lane];
        ax += v.x;
        ay += v.y;
    }
    unsigned short hx, lx, hy, ly;
    split_bf(ax, hx, lx);
    split_bf(ay, hy, ly);
    int mt = node >> 4, r16 = node & 15;
    int ks = lane >> 4, quad = (lane >> 2) & 3, jb = (lane * 2) & 7;
    size_t zo = (((size_t)(mt * 4 + ks)) * 4 + quad) * 128 + r16 * 8 + jb;
    *(ushort2*)(zfh + zo) = make_ushort2(hx, hy);
    *(ushort2*)(zfl + zo) = make_ushort2(lx, ly);
}

// ---- fused MLP, K-chunked LDS: hidden cols processed 128 at a time through a
// 16-plane wave-private LDS buffer (plane = (k>>3)&15, stride 136 shorts).
// grid (1563) ; block 128 = 2 waves x 16 rows.
__global__ __launch_bounds__(128) void mlp_kernel(
        const unsigned short* __restrict__ zfh, const unsigned short* __restrict__ zfl,
        const unsigned short* __restrict__ w1fh, const unsigned short* __restrict__ w1fl,
        const unsigned short* __restrict__ w2fh, const unsigned short* __restrict__ w2fl,
        const float* __restrict__ scale1, const float* __restrict__ shift1,
        const float* __restrict__ scale2, const float* __restrict__ shift2,
        int last,
        float* __restrict__ hout, float* __restrict__ lsout) {
    __shared__ unsigned short lds[2 * 2 * 2176];   // [wave][hi/lo][16 planes * 136]
    const int wave = threadIdx.x >> 6;
    const int lane = threadIdx.x & 63;
    const int quad = lane >> 4;
    const int l16 = lane & 15;
    const int R0 = blockIdx.x * 32 + wave * 16;
    const int mt = R0 >> 4;
    unsigned short* mh = lds + wave * 4352;
    unsigned short* ml = mh + 2176;

    // A fragments for phase 1 (16 rows x K=128), held in registers
    short8 ah[4], al[4];
    #pragma unroll
    for (int ks = 0; ks < 4; ++ks) {
        size_t o = (((size_t)(mt * 4 + ks)) << 9) + lane * 8;
        ah[ks] = *(const short8*)(zfh + o);
        al[ks] = *(const short8*)(zfl + o);
    }

    f32x4 acc2[8] = {};
    #pragma unroll
    for (int c = 0; c < 2; ++c) {
        // ---- phase 1 chunk: hidden cols [128c, 128c+128) -> LDS planes 0..15 ----
        #pragma unroll
        for (int ntl = 0; ntl < 8; ++ntl) {
            int nt = c * 8 + ntl;
            f32x4 acc = {};
            #pragma unroll
            for (int ks = 0; ks < 4; ++ks) {
                size_t o = (((size_t)(nt * 4 + ks)) << 9) + lane * 8;
                short8 bh = *(const short8*)(w1fh + o);
                short8 bl = *(const short8*)(w1fl + o);
                acc = __builtin_amdgcn_mfma_f32_16x16x32_bf16(ah[ks], bh, acc, 0, 0, 0);
                acc = __builtin_amdgcn_mfma_f32_16x16x32_bf16(ah[ks], bl, acc, 0, 0, 0);
                acc = __builtin_amdgcn_mfma_f32_16x16x32_bf16(al[ks], bh, acc, 0, 0, 0);
            }
            int cg = nt * 16 + l16;
            float sc = scale1[cg];
            float sh = shift1[cg];
            int plane = (cg >> 3) & 15;              // k>>3 within chunk
            int basei = plane * 136 + (cg & 7);
            #pragma unroll
            for (int r = 0; r < 4; ++r) {
                float val = fmaxf(acc[r] * sc + sh, 0.0f);
                unsigned short hi, lo;
                split_bf(val, hi, lo);
                int m = quad * 4 + r;
                mh[basei + m * 8] = hi;
                ml[basei + m * 8] = lo;
            }
        }
        // ---- phase 2 chunk: k in [128c, 128c+128) ----
        #pragma unroll
        for (int ks4 = 0; ks4 < 4; ++ks4) {
            int po = (ks4 * 4 + quad) * 136 + l16 * 8;
            short8 a2h = *(const short8*)&mh[po];
            short8 a2l = *(const short8*)&ml[po];
            int ksg = c * 4 + ks4;
            #pragma unroll
            for (int nt = 0; nt < 8; ++nt) {
                size_t ob = (((size_t)(nt * 8 + ksg)) << 9) + lane * 8;
                short8 bh = *(const short8*)(w2fh + ob);
                short8 bl = *(const short8*)(w2fl + ob);
                acc2[nt] = __builtin_amdgcn_mfma_f32_16x16x32_bf16(a2h, bh, acc2[nt], 0, 0, 0);
                acc2[nt] = __builtin_amdgcn_mfma_f32_16x16x32_bf16(a2h, bl, acc2[nt], 0, 0, 0);
                acc2[nt] = __builtin_amdgcn_mfma_f32_16x16x32_bf16(a2l, bh, acc2[nt], 0, 0, 0);
            }
        }
    }

    // ---- epilogue 2 ----
    #pragma unroll
    for (int nt = 0; nt < 8; ++nt) {
        int cg = nt * 16 + l16;
        float sc = scale2[cg];
        float sh = shift2[cg];
        #pragma unroll
        for (int r = 0; r < 4; ++r)
            acc2[nt][r] = acc2[nt][r] * sc + sh;
    }
    if (!last) {
        #pragma unroll
        for (int nt = 0; nt < 8; ++nt) {
            int cg = nt * 16 + l16;
            #pragma unroll
            for (int r = 0; r < 4; ++r) {
                int rg = R0 + quad * 4 + r;
                if (rg < N_NODES)
                    hout[(size_t)rg * DIM + cg] = fmaxf(acc2[nt][r], 0.0f);
            }
        }
    } else {
        #pragma unroll
        for (int r = 0; r < 4; ++r) {
            float mx = acc2[0][r];
            #pragma unroll
            for (int nt = 1; nt < 8; ++nt) mx = fmaxf(mx, acc2[nt][r]);
            #pragma unroll
            for (int off = 1; off < 16; off <<= 1) mx = fmaxf(mx, __shfl_xor(mx, off, 64));
            float sum = 0.0f;
            #pragma unroll
            for (int nt = 0; nt < 8; ++nt) sum += expf(acc2[nt][r] - mx);
            #pragma unroll
            for (int off = 1; off < 16; off <<= 1) sum += __shfl_xor(sum, off, 64);
            float ls = mx + logf(sum);
            int rg = R0 + quad * 4 + r;
            if (rg < N_NODES) {
                #pragma unroll
                for (int nt = 0; nt < 8; ++nt)
                    lsout[(size_t)rg * DIM + nt * 16 + l16] = acc2[nt][r] - ls;
            }
        }
    }
}

extern "C" void kernel_launch(void* const* d_in, const int* in_sizes, int n_in,
                              void* d_out, int out_size, void* d_ws, size_t ws_size,
                              hipStream_t stream) {
    const float* x   = (const float*)d_in[0];
    const int*   ei  = (const int*)d_in[1];
    const float* W1  = (const float*)d_in[2];
    const float* b1  = (const float*)d_in[3];
    const float* g1  = (const float*)d_in[4];
    const float* be1 = (const float*)d_in[5];
    const float* m1  = (const float*)d_in[6];
    const float* v1  = (const float*)d_in[7];
    const float* W2  = (const float*)d_in[8];
    const float* b2  = (const float*)d_in[9];
    const float* eps = (const float*)d_in[10];
    const float* go  = (const float*)d_in[11];
    const float* bo  = (const float*)d_in[12];
    const float* mo  = (const float*)d_in[13];
    const float* vo  = (const float*)d_in[14];

    const size_t MT = 3126;                     // ceil(50016/16) row tiles
    char* ws = (char*)d_ws;
    float* h = (float*)ws;                      ws += (size_t)N_NODES * DIM * 4;
    unsigned short* zfh = (unsigned short*)ws;  ws += MT * 2048 * 2;
    unsigned short* zfl = (unsigned short*)ws;  ws += MT * 2048 * 2;
    unsigned short* w1fh = (unsigned short*)ws; ws += (size_t)L_LAYERS * 32768 * 2;
    unsigned short* w1fl = (unsigned short*)ws; ws += (size_t)L_LAYERS * 32768 * 2;
    unsigned short* w2fh = (unsigned short*)ws; ws += (size_t)L_LAYERS * 32768 * 2;
    unsigned short* w2fl = (unsigned short*)ws; ws += (size_t)L_LAYERS * 32768 * 2;
    float* scale1 = (float*)ws; ws += (size_t)L_LAYERS * 256 * 4;
    float* shift1 = (float*)ws; ws += (size_t)L_LAYERS * 256 * 4;
    float* scale2 = (float*)ws; ws += (size_t)L_LAYERS * 128 * 4;
    float* shift2 = (float*)ws; ws += (size_t)L_LAYERS * 128 * 4;
    int* deg    = (int*)ws; ws += (size_t)N_NODES * 4;
    int* rowtmp = (int*)ws; ws += (size_t)N_NODES * 4;
    int* rowp   = (int*)ws; ws += (size_t)(N_NODES + 1) * 4;
    int* cursor = (int*)ws; ws += (size_t)N_NODES * 4;
    int* bsum   = (int*)ws; ws += 256 * 4;
    int* col    = (int*)ws; ws += (size_t)E_EDGES * 4;

    // ---- CSR build (graph is layer-invariant) ----
    hipMemsetAsync(deg, 0, (size_t)N_NODES * 4, stream);
    histogram_kernel<<<E_EDGES / 256, 256, 0, stream>>>(ei, deg);
    scan1_kernel<<<SCAN_BLOCKS, 256, 0, stream>>>(deg, rowtmp, bsum);
    scan2_kernel<<<1, 256, 0, stream>>>(bsum);
    scan3_kernel<<<SCAN_BLOCKS, 256, 0, stream>>>(rowtmp, bsum, rowp, cursor);
    fill_kernel<<<E_EDGES / 256, 256, 0, stream>>>(ei, cursor, col);

    trans_split_kernel<<<(L_LAYERS * DIM * 2 * DIM) / 256, 256, 0, stream>>>(W1, w1fh, w1fl, DIM, 2 * DIM);
    trans_split_kernel<<<(L_LAYERS * DIM * 2 * DIM) / 256, 256, 0, stream>>>(W2, w2fh, w2fl, 2 * DIM, DIM);
    prep_params_kernel<<<5, 256, 0, stream>>>(b1, g1, be1, m1, v1, b2, go, bo, mo, vo,
                                              scale1, shift1, scale2, shift2);

    for (int i = 0; i < L_LAYERS; ++i) {
        const float* hsrc = (i == 0) ? x : h;
        aggregate_kernel<<<N_NODES / 4, 256, 0, stream>>>(hsrc, rowp, col, eps + i, zfh, zfl);
        int last = (i == L_LAYERS - 1) ? 1 : 0;
        mlp_kernel<<<MBLK, 128, 0, stream>>>(zfh, zfl,
            w1fh + (size_t)i * 32768, w1fl + (size_t)i * 32768,
            w2fh + (size_t)i * 32768, w2fl + (size_t)i * 32768,
            scale1 + i * 256, shift1 + i * 256,
            scale2 + i * 128, shift2 + i * 128,
            last, h, (float*)d_out);
    }
}

// Round 8
// 434.701 us; speedup vs baseline: 1.9302x; 1.3195x over previous
//
#include <hip/hip_runtime.h>
#include <hip/hip_bf16.h>

#define N_NODES 50000
#define DIM 128
#define E_EDGES 800000
#define L_LAYERS 3
#define SCAN_BLOCKS 196   // ceil(50000/256)
#define MTILES 3125       // 50000/16 exactly

typedef __attribute__((ext_vector_type(8))) short short8;
typedef __attribute__((ext_vector_type(4))) float f32x4;
typedef __attribute__((ext_vector_type(2))) _Float16 f16x2;
typedef __attribute__((ext_vector_type(4))) _Float16 f16x4;

__device__ __forceinline__ float bf_to_f(unsigned short u) {
    unsigned int x = ((unsigned int)u) << 16;
    return __builtin_bit_cast(float, x);
}
__device__ __forceinline__ unsigned short f_to_bf(float f) {
    unsigned int x = __builtin_bit_cast(unsigned int, f);
    unsigned int lsb = (x >> 16) & 1u;
    x += 0x7fffu + lsb;   // round-to-nearest-even
    return (unsigned short)(x >> 16);
}
__device__ __forceinline__ void split_bf(float f, unsigned short& hi, unsigned short& lo) {
    hi = f_to_bf(f);
    lo = f_to_bf(f - bf_to_f(hi));
}

// ---- x fp32 -> fp16 ----
__global__ __launch_bounds__(256) void cvt16_kernel(const float4* __restrict__ in,
                                                    f16x4* __restrict__ out) {
    int i = blockIdx.x * 256 + threadIdx.x;
    float4 v = in[i];
    f16x4 o;
    o[0] = (_Float16)v.x; o[1] = (_Float16)v.y;
    o[2] = (_Float16)v.z; o[3] = (_Float16)v.w;
    out[i] = o;
}

// ---- W1,W2 [L][K][Nn] fp32 -> fragment-contiguous split bf16 (both in one) ----
__global__ __launch_bounds__(256) void trans_split_kernel(
        const float* __restrict__ w1, const float* __restrict__ w2,
        unsigned short* __restrict__ f1h, unsigned short* __restrict__ f1l,
        unsigned short* __restrict__ f2h, unsigned short* __restrict__ f2l) {
    int idx = blockIdx.x * 256 + threadIdx.x;
    const int per = DIM * 2 * DIM;             // 32768
    const int tot = L_LAYERS * per;
    const float* w;
    unsigned short *fh, *fl;
    int K, Nn, id;
    if (idx < tot) { w = w1; fh = f1h; fl = f1l; K = DIM; Nn = 2 * DIM; id = idx; }
    else           { w = w2; fh = f2h; fl = f2l; K = 2 * DIM; Nn = DIM; id = idx - tot; }
    int l = id / per;
    int r = id - l * per;
    int k = r / Nn;
    int n = r - k * Nn;
    int KS = K >> 5;
    int off = ((((n >> 4) * KS + (k >> 5)) * 4 + ((k >> 3) & 3)) * 16 + (n & 15)) * 8 + (k & 7);
    unsigned short hi, lo;
    split_bf(w[id], hi, lo);
    fh[(size_t)l * per + off] = hi;
    fl[(size_t)l * per + off] = lo;
}

// ---- fold bias+BN into per-channel scale/shift ----
__global__ __launch_bounds__(256) void prep_params_kernel(
        const float* __restrict__ b1, const float* __restrict__ g1,
        const float* __restrict__ be1, const float* __restrict__ m1,
        const float* __restrict__ v1, const float* __restrict__ b2,
        const float* __restrict__ go, const float* __restrict__ bo,
        const float* __restrict__ mo, const float* __restrict__ vo,
        float* __restrict__ scale1, float* __restrict__ shift1,
        float* __restrict__ scale2, float* __restrict__ shift2) {
    int idx = blockIdx.x * 256 + threadIdx.x;
    if (idx < L_LAYERS * 256) {
        float s = g1[idx] * rsqrtf(v1[idx] + 1e-5f);
        scale1[idx] = s;
        shift1[idx] = (b1[idx] - m1[idx]) * s + be1[idx];
    }
    int idx2 = idx - L_LAYERS * 256;
    if (idx2 >= 0 && idx2 < L_LAYERS * 128) {
        int l = idx2 >> 7;
        if (l < L_LAYERS - 1) {
            float s = go[idx2] * rsqrtf(vo[idx2] + 1e-5f);
            scale2[idx2] = s;
            shift2[idx2] = (b2[idx2] - mo[idx2]) * s + bo[idx2];
        } else {
            scale2[idx2] = 1.0f;
            shift2[idx2] = b2[idx2];
        }
    }
}

// ================= CSR build (once per call; graph shared by all layers) ====

__global__ __launch_bounds__(256) void histogram_kernel(const int* __restrict__ ei,
                                                        int* __restrict__ deg) {
    int e = blockIdx.x * 256 + threadIdx.x;
    atomicAdd(&deg[ei[E_EDGES + e]], 1);
}

__global__ __launch_bounds__(256) void scan1_kernel(const int* __restrict__ deg,
                                                    int* __restrict__ rowtmp,
                                                    int* __restrict__ bsum) {
    __shared__ int s[256];
    int t = threadIdx.x;
    int idx = blockIdx.x * 256 + t;
    int v = (idx < N_NODES) ? deg[idx] : 0;
    s[t] = v;
    __syncthreads();
    for (int off = 1; off < 256; off <<= 1) {
        int x = s[t];
        int y = (t >= off) ? s[t - off] : 0;
        __syncthreads();
        s[t] = x + y;
        __syncthreads();
    }
    if (idx < N_NODES) rowtmp[idx] = s[t] - v;
    if (t == 255) bsum[blockIdx.x] = s[255];
}

__global__ __launch_bounds__(256) void scan2_kernel(int* __restrict__ bsum) {
    __shared__ int s[256];
    int t = threadIdx.x;
    int v = (t < SCAN_BLOCKS) ? bsum[t] : 0;
    s[t] = v;
    __syncthreads();
    for (int off = 1; off < 256; off <<= 1) {
        int x = s[t];
        int y = (t >= off) ? s[t - off] : 0;
        __syncthreads();
        s[t] = x + y;
        __syncthreads();
    }
    if (t < SCAN_BLOCKS) bsum[t] = s[t] - v;   // exclusive
}

__global__ __launch_bounds__(256) void scan3_kernel(const int* __restrict__ rowtmp,
                                                    const int* __restrict__ bsum,
                                                    int* __restrict__ row,
                                                    int* __restrict__ cursor) {
    int idx = blockIdx.x * 256 + threadIdx.x;
    if (idx < N_NODES) {
        int rs = rowtmp[idx] + bsum[blockIdx.x];
        row[idx] = rs;
        cursor[idx] = rs;
    }
    if (idx == 0) row[N_NODES] = E_EDGES;
}

__global__ __launch_bounds__(256) void fill_kernel(const int* __restrict__ ei,
                                                   int* __restrict__ cursor,
                                                   int* __restrict__ col) {
    int e = blockIdx.x * 256 + threadIdx.x;
    int dst = ei[E_EDGES + e];
    int pos = atomicAdd(&cursor[dst], 1);
    col[pos] = ei[e];
}

// ---- aggregation: z = (1+eps)*h[i] + sum_j h[j]; h is fp16; out split-bf16 frag order ----
// one wave per node; lane owns cols 2*lane, 2*lane+1 (one f16x2 = 4 B)
__global__ __launch_bounds__(256) void aggregate_kernel(
        const unsigned int* __restrict__ h16,    // raw f16x2 words
        const int* __restrict__ row, const int* __restrict__ col,
        const float* __restrict__ epsp,
        unsigned short* __restrict__ zfh, unsigned short* __restrict__ zfl) {
    int wv = threadIdx.x >> 6;
    int lane = threadIdx.x & 63;
    int node = blockIdx.x * 4 + wv;                  // grid = 12500 exactly
    size_t base = (size_t)node * 64;                 // row stride = 64 f16x2 words
    float s = 1.0f + epsp[0];
    f16x2 hv = __builtin_bit_cast(f16x2, h16[base + lane]);
    float ax = s * (float)hv[0], ay = s * (float)hv[1];
    int e = row[node], e1 = row[node + 1];
    for (; e + 8 <= e1; e += 8) {
        int c0 = col[e],     c1 = col[e + 1], c2 = col[e + 2], c3 = col[e + 3];
        int c4 = col[e + 4], c5 = col[e + 5], c6 = col[e + 6], c7 = col[e + 7];
        f16x2 v0 = __builtin_bit_cast(f16x2, h16[(size_t)c0 * 64 + lane]);
        f16x2 v1 = __builtin_bit_cast(f16x2, h16[(size_t)c1 * 64 + lane]);
        f16x2 v2 = __builtin_bit_cast(f16x2, h16[(size_t)c2 * 64 + lane]);
        f16x2 v3 = __builtin_bit_cast(f16x2, h16[(size_t)c3 * 64 + lane]);
        f16x2 v4 = __builtin_bit_cast(f16x2, h16[(size_t)c4 * 64 + lane]);
        f16x2 v5 = __builtin_bit_cast(f16x2, h16[(size_t)c5 * 64 + lane]);
        f16x2 v6 = __builtin_bit_cast(f16x2, h16[(size_t)c6 * 64 + lane]);
        f16x2 v7 = __builtin_bit_cast(f16x2, h16[(size_t)c7 * 64 + lane]);
        ax += (((float)v0[0] + (float)v1[0]) + ((float)v2[0] + (float)v3[0]))
            + (((float)v4[0] + (float)v5[0]) + ((float)v6[0] + (float)v7[0]));
        ay += (((float)v0[1] + (float)v1[1]) + ((float)v2[1] + (float)v3[1]))
            + (((float)v4[1] + (float)v5[1]) + ((float)v6[1] + (float)v7[1]));
    }
    for (; e < e1; ++e) {
        f16x2 v = __builtin_bit_cast(f16x2, h16[(size_t)col[e] * 64 + lane]);
        ax += (float)v[0];
        ay += (float)v[1];
    }
    unsigned short hx, lx, hy, ly;
    split_bf(ax, hx, lx);
    split_bf(ay, hy, ly);
    int mt = node >> 4, r16 = node & 15;
    int ks = lane >> 4, quad = (lane >> 2) & 3, jb = (lane * 2) & 7;
    size_t zo = (((size_t)(mt * 4 + ks)) * 4 + quad) * 128 + r16 * 8 + jb;
    *(ushort2*)(zfh + zo) = make_ushort2(hx, hy);
    *(ushort2*)(zfl + zo) = make_ushort2(lx, ly);
}

// ---- fused MLP, 1 wave per block (16 rows), K-chunked wave-private LDS ----
// grid = 3125 (50000/16 exact); LDS 8704 B/block -> ~12 blocks/CU by grid.
__global__ __launch_bounds__(64) void mlp_kernel(
        const unsigned short* __restrict__ zfh, const unsigned short* __restrict__ zfl,
        const unsigned short* __restrict__ w1fh, const unsigned short* __restrict__ w1fl,
        const unsigned short* __restrict__ w2fh, const unsigned short* __restrict__ w2fl,
        const float* __restrict__ scale1, const float* __restrict__ shift1,
        const float* __restrict__ scale2, const float* __restrict__ shift2,
        int last,
        unsigned short* __restrict__ h16out, float* __restrict__ lsout) {
    __shared__ unsigned short mh[2176];   // 16 planes * 136
    __shared__ unsigned short ml[2176];
    const int lane = threadIdx.x;
    const int quad = lane >> 4;
    const int l16 = lane & 15;
    const int mt = blockIdx.x;
    const int R0 = mt * 16;

    short8 ah[4], al[4];
    #pragma unroll
    for (int ks = 0; ks < 4; ++ks) {
        size_t o = (((size_t)(mt * 4 + ks)) << 9) + lane * 8;
        ah[ks] = *(const short8*)(zfh + o);
        al[ks] = *(const short8*)(zfl + o);
    }

    f32x4 acc2[8] = {};
    #pragma unroll
    for (int c = 0; c < 2; ++c) {
        // phase 1 chunk: hidden cols [128c, 128c+128) -> LDS planes 0..15
        #pragma unroll
        for (int ntl = 0; ntl < 8; ++ntl) {
            int nt = c * 8 + ntl;
            f32x4 acc = {};
            #pragma unroll
            for (int ks = 0; ks < 4; ++ks) {
                size_t o = (((size_t)(nt * 4 + ks)) << 9) + lane * 8;
                short8 bh = *(const short8*)(w1fh + o);
                short8 bl = *(const short8*)(w1fl + o);
                acc = __builtin_amdgcn_mfma_f32_16x16x32_bf16(ah[ks], bh, acc, 0, 0, 0);
                acc = __builtin_amdgcn_mfma_f32_16x16x32_bf16(ah[ks], bl, acc, 0, 0, 0);
                acc = __builtin_amdgcn_mfma_f32_16x16x32_bf16(al[ks], bh, acc, 0, 0, 0);
            }
            int cg = nt * 16 + l16;
            float sc = scale1[cg];
            float sh = shift1[cg];
            int plane = (cg >> 3) & 15;
            int basei = plane * 136 + (cg & 7);
            #pragma unroll
            for (int r = 0; r < 4; ++r) {
                float val = fmaxf(acc[r] * sc + sh, 0.0f);
                unsigned short hi, lo;
                split_bf(val, hi, lo);
                int m = quad * 4 + r;
                mh[basei + m * 8] = hi;
                ml[basei + m * 8] = lo;
            }
        }
        // phase 2 chunk: k in [128c, 128c+128)
        #pragma unroll
        for (int ks4 = 0; ks4 < 4; ++ks4) {
            int po = (ks4 * 4 + quad) * 136 + l16 * 8;
            short8 a2h = *(const short8*)&mh[po];
            short8 a2l = *(const short8*)&ml[po];
            int ksg = c * 4 + ks4;
            #pragma unroll
            for (int nt = 0; nt < 8; ++nt) {
                size_t ob = (((size_t)(nt * 8 + ksg)) << 9) + lane * 8;
                short8 bh = *(const short8*)(w2fh + ob);
                short8 bl = *(const short8*)(w2fl + ob);
                acc2[nt] = __builtin_amdgcn_mfma_f32_16x16x32_bf16(a2h, bh, acc2[nt], 0, 0, 0);
                acc2[nt] = __builtin_amdgcn_mfma_f32_16x16x32_bf16(a2h, bl, acc2[nt], 0, 0, 0);
                acc2[nt] = __builtin_amdgcn_mfma_f32_16x16x32_bf16(a2l, bh, acc2[nt], 0, 0, 0);
            }
        }
    }

    #pragma unroll
    for (int nt = 0; nt < 8; ++nt) {
        int cg = nt * 16 + l16;
        float sc = scale2[cg];
        float sh = shift2[cg];
        #pragma unroll
        for (int r = 0; r < 4; ++r)
            acc2[nt][r] = acc2[nt][r] * sc + sh;
    }
    if (!last) {
        #pragma unroll
        for (int nt = 0; nt < 8; ++nt) {
            int cg = nt * 16 + l16;
            #pragma unroll
            for (int r = 0; r < 4; ++r) {
                int rg = R0 + quad * 4 + r;
                float val = fmaxf(acc2[nt][r], 0.0f);
                h16out[(size_t)rg * DIM + cg] =
                    __builtin_bit_cast(unsigned short, (_Float16)val);
            }
        }
    } else {
        #pragma unroll
        for (int r = 0; r < 4; ++r) {
            float mx = acc2[0][r];
            #pragma unroll
            for (int nt = 1; nt < 8; ++nt) mx = fmaxf(mx, acc2[nt][r]);
            #pragma unroll
            for (int off = 1; off < 16; off <<= 1) mx = fmaxf(mx, __shfl_xor(mx, off, 64));
            float sum = 0.0f;
            #pragma unroll
            for (int nt = 0; nt < 8; ++nt) sum += expf(acc2[nt][r] - mx);
            #pragma unroll
            for (int off = 1; off < 16; off <<= 1) sum += __shfl_xor(sum, off, 64);
            float ls = mx + logf(sum);
            int rg = R0 + quad * 4 + r;
            #pragma unroll
            for (int nt = 0; nt < 8; ++nt)
                lsout[(size_t)rg * DIM + nt * 16 + l16] = acc2[nt][r] - ls;
        }
    }
}

extern "C" void kernel_launch(void* const* d_in, const int* in_sizes, int n_in,
                              void* d_out, int out_size, void* d_ws, size_t ws_size,
                              hipStream_t stream) {
    const float* x   = (const float*)d_in[0];
    const int*   ei  = (const int*)d_in[1];
    const float* W1  = (const float*)d_in[2];
    const float* b1  = (const float*)d_in[3];
    const float* g1  = (const float*)d_in[4];
    const float* be1 = (const float*)d_in[5];
    const float* m1  = (const float*)d_in[6];
    const float* v1  = (const float*)d_in[7];
    const float* W2  = (const float*)d_in[8];
    const float* b2  = (const float*)d_in[9];
    const float* eps = (const float*)d_in[10];
    const float* go  = (const float*)d_in[11];
    const float* bo  = (const float*)d_in[12];
    const float* mo  = (const float*)d_in[13];
    const float* vo  = (const float*)d_in[14];

    char* ws = (char*)d_ws;
    unsigned short* h16 = (unsigned short*)ws;  ws += (size_t)N_NODES * DIM * 2;   // 12.8 MB
    unsigned short* zfh = (unsigned short*)ws;  ws += (size_t)MTILES * 2048 * 2;
    unsigned short* zfl = (unsigned short*)ws;  ws += (size_t)MTILES * 2048 * 2;
    unsigned short* w1fh = (unsigned short*)ws; ws += (size_t)L_LAYERS * 32768 * 2;
    unsigned short* w1fl = (unsigned short*)ws; ws += (size_t)L_LAYERS * 32768 * 2;
    unsigned short* w2fh = (unsigned short*)ws; ws += (size_t)L_LAYERS * 32768 * 2;
    unsigned short* w2fl = (unsigned short*)ws; ws += (size_t)L_LAYERS * 32768 * 2;
    float* scale1 = (float*)ws; ws += (size_t)L_LAYERS * 256 * 4;
    float* shift1 = (float*)ws; ws += (size_t)L_LAYERS * 256 * 4;
    float* scale2 = (float*)ws; ws += (size_t)L_LAYERS * 128 * 4;
    float* shift2 = (float*)ws; ws += (size_t)L_LAYERS * 128 * 4;
    int* deg    = (int*)ws; ws += (size_t)N_NODES * 4;
    int* rowtmp = (int*)ws; ws += (size_t)N_NODES * 4;
    int* rowp   = (int*)ws; ws += (size_t)(N_NODES + 1) * 4;
    int* cursor = (int*)ws; ws += (size_t)N_NODES * 4;
    int* bsum   = (int*)ws; ws += 256 * 4;
    int* col    = (int*)ws; ws += (size_t)E_EDGES * 4;

    // ---- CSR build ----
    hipMemsetAsync(deg, 0, (size_t)N_NODES * 4, stream);
    histogram_kernel<<<E_EDGES / 256, 256, 0, stream>>>(ei, deg);
    scan1_kernel<<<SCAN_BLOCKS, 256, 0, stream>>>(deg, rowtmp, bsum);
    scan2_kernel<<<1, 256, 0, stream>>>(bsum);
    scan3_kernel<<<SCAN_BLOCKS, 256, 0, stream>>>(rowtmp, bsum, rowp, cursor);
    fill_kernel<<<E_EDGES / 256, 256, 0, stream>>>(ei, cursor, col);

    cvt16_kernel<<<(N_NODES * DIM / 4) / 256, 256, 0, stream>>>((const float4*)x, (f16x4*)h16);
    trans_split_kernel<<<(2 * L_LAYERS * DIM * 2 * DIM) / 256, 256, 0, stream>>>(
        W1, W2, w1fh, w1fl, w2fh, w2fl);
    prep_params_kernel<<<5, 256, 0, stream>>>(b1, g1, be1, m1, v1, b2, go, bo, mo, vo,
                                              scale1, shift1, scale2, shift2);

    for (int i = 0; i < L_LAYERS; ++i) {
        aggregate_kernel<<<N_NODES / 4, 256, 0, stream>>>((const unsigned int*)h16,
                                                          rowp, col, eps + i, zfh, zfl);
        int last = (i == L_LAYERS - 1) ? 1 : 0;
        mlp_kernel<<<MTILES, 64, 0, stream>>>(zfh, zfl,
            w1fh + (size_t)i * 32768, w1fl + (size_t)i * 32768,
            w2fh + (size_t)i * 32768, w2fl + (size_t)i * 32768,
            scale1 + i * 256, shift1 + i * 256,
            scale2 + i * 128, shift2 + i * 128,
            last, h16, (float*)d_out);
    }
}

// Round 9
// 383.801 us; speedup vs baseline: 2.1862x; 1.1326x over previous
//
#include <hip/hip_runtime.h>
#include <hip/hip_bf16.h>

#define N_NODES 50000
#define DIM 128
#define E_EDGES 800000
#define L_LAYERS 3
#define MTILES 3125       // 50000/16 exactly
#define NBUCK 98          // ceil(50000/512)
#define BCAP 9216         // bucket capacity: mean 8192 + 11 sigma
#define BSHIFT 9          // 512 nodes per bucket

typedef __attribute__((ext_vector_type(8))) short short8;
typedef __attribute__((ext_vector_type(4))) float f32x4;
typedef __attribute__((ext_vector_type(2))) _Float16 f16x2;
typedef __attribute__((ext_vector_type(4))) _Float16 f16x4;

__device__ __forceinline__ float bf_to_f(unsigned short u) {
    unsigned int x = ((unsigned int)u) << 16;
    return __builtin_bit_cast(float, x);
}
__device__ __forceinline__ unsigned short f_to_bf(float f) {
    unsigned int x = __builtin_bit_cast(unsigned int, f);
    unsigned int lsb = (x >> 16) & 1u;
    x += 0x7fffu + lsb;   // round-to-nearest-even
    return (unsigned short)(x >> 16);
}
__device__ __forceinline__ void split_bf(float f, unsigned short& hi, unsigned short& lo) {
    hi = f_to_bf(f);
    lo = f_to_bf(f - bf_to_f(hi));
}

// ---- x fp32 -> fp16 ----
__global__ __launch_bounds__(256) void cvt16_kernel(const float4* __restrict__ in,
                                                    f16x4* __restrict__ out) {
    int i = blockIdx.x * 256 + threadIdx.x;
    float4 v = in[i];
    f16x4 o;
    o[0] = (_Float16)v.x; o[1] = (_Float16)v.y;
    o[2] = (_Float16)v.z; o[3] = (_Float16)v.w;
    out[i] = o;
}

// ---- W1,W2 [L][K][Nn] fp32 -> fragment-contiguous split bf16 ----
__global__ __launch_bounds__(256) void trans_split_kernel(
        const float* __restrict__ w1, const float* __restrict__ w2,
        unsigned short* __restrict__ f1h, unsigned short* __restrict__ f1l,
        unsigned short* __restrict__ f2h, unsigned short* __restrict__ f2l) {
    int idx = blockIdx.x * 256 + threadIdx.x;
    const int per = DIM * 2 * DIM;             // 32768
    const int tot = L_LAYERS * per;
    const float* w;
    unsigned short *fh, *fl;
    int K, Nn, id;
    if (idx < tot) { w = w1; fh = f1h; fl = f1l; K = DIM; Nn = 2 * DIM; id = idx; }
    else           { w = w2; fh = f2h; fl = f2l; K = 2 * DIM; Nn = DIM; id = idx - tot; }
    int l = id / per;
    int r = id - l * per;
    int k = r / Nn;
    int n = r - k * Nn;
    int KS = K >> 5;
    int off = ((((n >> 4) * KS + (k >> 5)) * 4 + ((k >> 3) & 3)) * 16 + (n & 15)) * 8 + (k & 7);
    unsigned short hi, lo;
    split_bf(w[id], hi, lo);
    fh[(size_t)l * per + off] = hi;
    fl[(size_t)l * per + off] = lo;
}

// ---- fold bias+BN into per-channel scale/shift ----
__global__ __launch_bounds__(256) void prep_params_kernel(
        const float* __restrict__ b1, const float* __restrict__ g1,
        const float* __restrict__ be1, const float* __restrict__ m1,
        const float* __restrict__ v1, const float* __restrict__ b2,
        const float* __restrict__ go, const float* __restrict__ bo,
        const float* __restrict__ mo, const float* __restrict__ vo,
        float* __restrict__ scale1, float* __restrict__ shift1,
        float* __restrict__ scale2, float* __restrict__ shift2) {
    int idx = blockIdx.x * 256 + threadIdx.x;
    if (idx < L_LAYERS * 256) {
        float s = g1[idx] * rsqrtf(v1[idx] + 1e-5f);
        scale1[idx] = s;
        shift1[idx] = (b1[idx] - m1[idx]) * s + be1[idx];
    }
    int idx2 = idx - L_LAYERS * 256;
    if (idx2 >= 0 && idx2 < L_LAYERS * 128) {
        int l = idx2 >> 7;
        if (l < L_LAYERS - 1) {
            float s = go[idx2] * rsqrtf(vo[idx2] + 1e-5f);
            scale2[idx2] = s;
            shift2[idx2] = (b2[idx2] - mo[idx2]) * s + bo[idx2];
        } else {
            scale2[idx2] = 1.0f;
            shift2[idx2] = b2[idx2];
        }
    }
}

// ================= binned CSR build =================

__global__ void initcur_kernel(int* __restrict__ gcur) {
    int t = threadIdx.x;
    if (t < NBUCK) gcur[t] = t * BCAP;
}

// bin 4096 edges/block into 98 buckets via LDS, copy out in contiguous bursts
__global__ __launch_bounds__(256) void bin_kernel(const int* __restrict__ ei,
                                                  int* __restrict__ gcur,
                                                  unsigned int* __restrict__ brec) {
    __shared__ int cnt[NBUCK];
    __shared__ int off[NBUCK];
    __shared__ int gbase[NBUCK];
    __shared__ unsigned int rec[4096];
    const int t = threadIdx.x;
    const int start = blockIdx.x * 4096;
    for (int i = t; i < NBUCK; i += 256) cnt[i] = 0;
    __syncthreads();
    unsigned int myrec[16];
    unsigned int mypos[16];
    int nmine = 0;
    #pragma unroll
    for (int i = 0; i < 16; ++i) {
        int e = start + i * 256 + t;
        if (e < E_EDGES) {
            int src = ei[e];
            int dst = ei[E_EDGES + e];
            int b = dst >> BSHIFT;
            int idx = atomicAdd(&cnt[b], 1);
            myrec[i] = ((unsigned int)(dst & 511) << 16) | (unsigned int)src;
            mypos[i] = ((unsigned int)b << 16) | (unsigned int)idx;
            nmine = i + 1;
        }
    }
    __syncthreads();
    if (t == 0) {
        int s = 0;
        for (int b = 0; b < NBUCK; ++b) { off[b] = s; s += cnt[b]; }
    }
    __syncthreads();
    #pragma unroll
    for (int i = 0; i < 16; ++i) {
        if (i < nmine) {
            int b = mypos[i] >> 16;
            int idx = mypos[i] & 0xFFFF;
            rec[off[b] + idx] = myrec[i];
        }
    }
    __syncthreads();
    if (t < NBUCK && cnt[t] > 0) gbase[t] = atomicAdd(&gcur[t], cnt[t]);
    __syncthreads();
    const int wv = t >> 6, lane = t & 63;
    for (int b = wv; b < NBUCK; b += 4) {
        int c = cnt[b], o = off[b], g = gbase[b];
        for (int j = lane; j < c; j += 64)
            brec[g + j] = rec[o + j];
    }
}

// scan bucket counts -> col base offsets; set rowp[N]
__global__ void bscan_kernel(const int* __restrict__ gcur, int* __restrict__ colbase,
                             int* __restrict__ rowp) {
    if (threadIdx.x == 0) {
        int s = 0;
        for (int b = 0; b < NBUCK; ++b) {
            colbase[b] = s;
            s += gcur[b] - b * BCAP;
        }
        rowp[N_NODES] = E_EDGES;
    }
}

// per-bucket counting sort by local dst -> rowp + sequential u16 col writes
__global__ __launch_bounds__(256) void bsort_kernel(const unsigned int* __restrict__ brec,
                                                    const int* __restrict__ gcur,
                                                    const int* __restrict__ colbase,
                                                    int* __restrict__ rowp,
                                                    unsigned short* __restrict__ col) {
    __shared__ int ncnt[512];
    __shared__ int noff[512];
    __shared__ int wsum[4];
    __shared__ unsigned short srcbuf[BCAP];
    const int b = blockIdx.x;
    const int t = threadIdx.x;
    const int lane = t & 63;
    const int wv = t >> 6;
    const int cnt = gcur[b] - b * BCAP;
    const unsigned int* r = brec + (size_t)b * BCAP;
    for (int i = t; i < 512; i += 256) ncnt[i] = 0;
    __syncthreads();
    for (int j = t; j < cnt; j += 256)
        atomicAdd(&ncnt[r[j] >> 16], 1);
    __syncthreads();
    // parallel exclusive scan over 512: thread t owns elems 2t, 2t+1
    int a0 = ncnt[2 * t], a1 = ncnt[2 * t + 1];
    int pair = a0 + a1;
    int inc = pair;
    #pragma unroll
    for (int d = 1; d < 64; d <<= 1) {
        int u = __shfl_up(inc, d, 64);
        if (lane >= d) inc += u;
    }
    if (lane == 63) wsum[wv] = inc;
    __syncthreads();
    int wo = 0;
    if (wv > 0) wo = wsum[0];
    if (wv > 1) wo += wsum[1];
    if (wv > 2) wo += wsum[2];
    int excl = wo + inc - pair;
    noff[2 * t] = excl;
    noff[2 * t + 1] = excl + a0;
    __syncthreads();
    // write rowp (coalesced)
    const int n0 = b << BSHIFT;
    const int cb = colbase[b];
    for (int i = t; i < 512; i += 256) {
        int node = n0 + i;
        if (node < N_NODES) rowp[node] = cb + noff[i];
    }
    // reuse ncnt as cursors
    for (int i = t; i < 512; i += 256) ncnt[i] = noff[i];
    __syncthreads();
    for (int j = t; j < cnt; j += 256) {
        unsigned int v = r[j];
        int pos = atomicAdd(&ncnt[v >> 16], 1);
        srcbuf[pos] = (unsigned short)(v & 0xFFFFu);
    }
    __syncthreads();
    unsigned short* cp = col + cb;
    for (int j = t; j < cnt; j += 256) cp[j] = srcbuf[j];
}

// ---- aggregation: z = (1+eps)*h[i] + sum_j h[j]; h fp16, col u16 ----
__global__ __launch_bounds__(256) void aggregate_kernel(
        const unsigned int* __restrict__ h16,
        const int* __restrict__ row, const unsigned short* __restrict__ col,
        const float* __restrict__ epsp,
        unsigned short* __restrict__ zfh, unsigned short* __restrict__ zfl) {
    int wv = threadIdx.x >> 6;
    int lane = threadIdx.x & 63;
    int node = blockIdx.x * 4 + wv;                  // grid = 12500 exactly
    size_t base = (size_t)node * 64;
    float s = 1.0f + epsp[0];
    f16x2 hv = __builtin_bit_cast(f16x2, h16[base + lane]);
    float ax = s * (float)hv[0], ay = s * (float)hv[1];
    int e = row[node], e1 = row[node + 1];
    for (; e + 8 <= e1; e += 8) {
        int c0 = col[e],     c1 = col[e + 1], c2 = col[e + 2], c3 = col[e + 3];
        int c4 = col[e + 4], c5 = col[e + 5], c6 = col[e + 6], c7 = col[e + 7];
        f16x2 v0 = __builtin_bit_cast(f16x2, h16[(size_t)c0 * 64 + lane]);
        f16x2 v1 = __builtin_bit_cast(f16x2, h16[(size_t)c1 * 64 + lane]);
        f16x2 v2 = __builtin_bit_cast(f16x2, h16[(size_t)c2 * 64 + lane]);
        f16x2 v3 = __builtin_bit_cast(f16x2, h16[(size_t)c3 * 64 + lane]);
        f16x2 v4 = __builtin_bit_cast(f16x2, h16[(size_t)c4 * 64 + lane]);
        f16x2 v5 = __builtin_bit_cast(f16x2, h16[(size_t)c5 * 64 + lane]);
        f16x2 v6 = __builtin_bit_cast(f16x2, h16[(size_t)c6 * 64 + lane]);
        f16x2 v7 = __builtin_bit_cast(f16x2, h16[(size_t)c7 * 64 + lane]);
        ax += (((float)v0[0] + (float)v1[0]) + ((float)v2[0] + (float)v3[0]))
            + (((float)v4[0] + (float)v5[0]) + ((float)v6[0] + (float)v7[0]));
        ay += (((float)v0[1] + (float)v1[1]) + ((float)v2[1] + (float)v3[1]))
            + (((float)v4[1] + (float)v5[1]) + ((float)v6[1] + (float)v7[1]));
    }
    for (; e < e1; ++e) {
        f16x2 v = __builtin_bit_cast(f16x2, h16[(size_t)col[e] * 64 + lane]);
        ax += (float)v[0];
        ay += (float)v[1];
    }
    unsigned short hx, lx, hy, ly;
    split_bf(ax, hx, lx);
    split_bf(ay, hy, ly);
    int mt = node >> 4, r16 = node & 15;
    int ks = lane >> 4, quad = (lane >> 2) & 3, jb = (lane * 2) & 7;
    size_t zo = (((size_t)(mt * 4 + ks)) * 4 + quad) * 128 + r16 * 8 + jb;
    *(ushort2*)(zfh + zo) = make_ushort2(hx, hy);
    *(ushort2*)(zfl + zo) = make_ushort2(lx, ly);
}

// ---- fused MLP, 1 wave per block (16 rows), K-chunked wave-private LDS ----
__global__ __launch_bounds__(64) void mlp_kernel(
        const unsigned short* __restrict__ zfh, const unsigned short* __restrict__ zfl,
        const unsigned short* __restrict__ w1fh, const unsigned short* __restrict__ w1fl,
        const unsigned short* __restrict__ w2fh, const unsigned short* __restrict__ w2fl,
        const float* __restrict__ scale1, const float* __restrict__ shift1,
        const float* __restrict__ scale2, const float* __restrict__ shift2,
        int last,
        unsigned short* __restrict__ h16out, float* __restrict__ lsout) {
    __shared__ unsigned short mh[2176];   // 16 planes * 136
    __shared__ unsigned short ml[2176];
    const int lane = threadIdx.x;
    const int quad = lane >> 4;
    const int l16 = lane & 15;
    const int mt = blockIdx.x;
    const int R0 = mt * 16;

    short8 ah[4], al[4];
    #pragma unroll
    for (int ks = 0; ks < 4; ++ks) {
        size_t o = (((size_t)(mt * 4 + ks)) << 9) + lane * 8;
        ah[ks] = *(const short8*)(zfh + o);
        al[ks] = *(const short8*)(zfl + o);
    }

    f32x4 acc2[8] = {};
    #pragma unroll
    for (int c = 0; c < 2; ++c) {
        #pragma unroll
        for (int ntl = 0; ntl < 8; ++ntl) {
            int nt = c * 8 + ntl;
            f32x4 acc = {};
            #pragma unroll
            for (int ks = 0; ks < 4; ++ks) {
                size_t o = (((size_t)(nt * 4 + ks)) << 9) + lane * 8;
                short8 bh = *(const short8*)(w1fh + o);
                short8 bl = *(const short8*)(w1fl + o);
                acc = __builtin_amdgcn_mfma_f32_16x16x32_bf16(ah[ks], bh, acc, 0, 0, 0);
                acc = __builtin_amdgcn_mfma_f32_16x16x32_bf16(ah[ks], bl, acc, 0, 0, 0);
                acc = __builtin_amdgcn_mfma_f32_16x16x32_bf16(al[ks], bh, acc, 0, 0, 0);
            }
            int cg = nt * 16 + l16;
            float sc = scale1[cg];
            float sh = shift1[cg];
            int plane = (cg >> 3) & 15;
            int basei = plane * 136 + (cg & 7);
            #pragma unroll
            for (int r = 0; r < 4; ++r) {
                float val = fmaxf(acc[r] * sc + sh, 0.0f);
                unsigned short hi, lo;
                split_bf(val, hi, lo);
                int m = quad * 4 + r;
                mh[basei + m * 8] = hi;
                ml[basei + m * 8] = lo;
            }
        }
        #pragma unroll
        for (int ks4 = 0; ks4 < 4; ++ks4) {
            int po = (ks4 * 4 + quad) * 136 + l16 * 8;
            short8 a2h = *(const short8*)&mh[po];
            short8 a2l = *(const short8*)&ml[po];
            int ksg = c * 4 + ks4;
            #pragma unroll
            for (int nt = 0; nt < 8; ++nt) {
                size_t ob = (((size_t)(nt * 8 + ksg)) << 9) + lane * 8;
                short8 bh = *(const short8*)(w2fh + ob);
                short8 bl = *(const short8*)(w2fl + ob);
                acc2[nt] = __builtin_amdgcn_mfma_f32_16x16x32_bf16(a2h, bh, acc2[nt], 0, 0, 0);
                acc2[nt] = __builtin_amdgcn_mfma_f32_16x16x32_bf16(a2h, bl, acc2[nt], 0, 0, 0);
                acc2[nt] = __builtin_amdgcn_mfma_f32_16x16x32_bf16(a2l, bh, acc2[nt], 0, 0, 0);
            }
        }
    }

    #pragma unroll
    for (int nt = 0; nt < 8; ++nt) {
        int cg = nt * 16 + l16;
        float sc = scale2[cg];
        float sh = shift2[cg];
        #pragma unroll
        for (int r = 0; r < 4; ++r)
            acc2[nt][r] = acc2[nt][r] * sc + sh;
    }
    if (!last) {
        #pragma unroll
        for (int nt = 0; nt < 8; ++nt) {
            int cg = nt * 16 + l16;
            #pragma unroll
            for (int r = 0; r < 4; ++r) {
                int rg = R0 + quad * 4 + r;
                float val = fmaxf(acc2[nt][r], 0.0f);
                h16out[(size_t)rg * DIM + cg] =
                    __builtin_bit_cast(unsigned short, (_Float16)val);
            }
        }
    } else {
        #pragma unroll
        for (int r = 0; r < 4; ++r) {
            float mx = acc2[0][r];
            #pragma unroll
            for (int nt = 1; nt < 8; ++nt) mx = fmaxf(mx, acc2[nt][r]);
            #pragma unroll
            for (int off = 1; off < 16; off <<= 1) mx = fmaxf(mx, __shfl_xor(mx, off, 64));
            float sum = 0.0f;
            #pragma unroll
            for (int nt = 0; nt < 8; ++nt) sum += expf(acc2[nt][r] - mx);
            #pragma unroll
            for (int off = 1; off < 16; off <<= 1) sum += __shfl_xor(sum, off, 64);
            float ls = mx + logf(sum);
            int rg = R0 + quad * 4 + r;
            #pragma unroll
            for (int nt = 0; nt < 8; ++nt)
                lsout[(size_t)rg * DIM + nt * 16 + l16] = acc2[nt][r] - ls;
        }
    }
}

extern "C" void kernel_launch(void* const* d_in, const int* in_sizes, int n_in,
                              void* d_out, int out_size, void* d_ws, size_t ws_size,
                              hipStream_t stream) {
    const float* x   = (const float*)d_in[0];
    const int*   ei  = (const int*)d_in[1];
    const float* W1  = (const float*)d_in[2];
    const float* b1  = (const float*)d_in[3];
    const float* g1  = (const float*)d_in[4];
    const float* be1 = (const float*)d_in[5];
    const float* m1  = (const float*)d_in[6];
    const float* v1  = (const float*)d_in[7];
    const float* W2  = (const float*)d_in[8];
    const float* b2  = (const float*)d_in[9];
    const float* eps = (const float*)d_in[10];
    const float* go  = (const float*)d_in[11];
    const float* bo  = (const float*)d_in[12];
    const float* mo  = (const float*)d_in[13];
    const float* vo  = (const float*)d_in[14];

    char* ws = (char*)d_ws;
    unsigned short* h16 = (unsigned short*)ws;  ws += (size_t)N_NODES * DIM * 2;
    unsigned short* zfh = (unsigned short*)ws;  ws += (size_t)MTILES * 2048 * 2;
    unsigned short* zfl = (unsigned short*)ws;  ws += (size_t)MTILES * 2048 * 2;
    unsigned short* w1fh = (unsigned short*)ws; ws += (size_t)L_LAYERS * 32768 * 2;
    unsigned short* w1fl = (unsigned short*)ws; ws += (size_t)L_LAYERS * 32768 * 2;
    unsigned short* w2fh = (unsigned short*)ws; ws += (size_t)L_LAYERS * 32768 * 2;
    unsigned short* w2fl = (unsigned short*)ws; ws += (size_t)L_LAYERS * 32768 * 2;
    float* scale1 = (float*)ws; ws += (size_t)L_LAYERS * 256 * 4;
    float* shift1 = (float*)ws; ws += (size_t)L_LAYERS * 256 * 4;
    float* scale2 = (float*)ws; ws += (size_t)L_LAYERS * 128 * 4;
    float* shift2 = (float*)ws; ws += (size_t)L_LAYERS * 128 * 4;
    unsigned int* brec = (unsigned int*)ws; ws += (size_t)NBUCK * BCAP * 4;   // 3.6 MB
    int* gcur    = (int*)ws; ws += 128 * 4;
    int* colbase = (int*)ws; ws += 128 * 4;
    int* rowp    = (int*)ws; ws += (size_t)(N_NODES + 1) * 4;
    unsigned short* col = (unsigned short*)ws; ws += (size_t)E_EDGES * 2;

    // ---- binned CSR build ----
    initcur_kernel<<<1, 128, 0, stream>>>(gcur);
    bin_kernel<<<(E_EDGES + 4095) / 4096, 256, 0, stream>>>(ei, gcur, brec);
    bscan_kernel<<<1, 64, 0, stream>>>(gcur, colbase, rowp);
    bsort_kernel<<<NBUCK, 256, 0, stream>>>(brec, gcur, colbase, rowp, col);

    cvt16_kernel<<<(N_NODES * DIM / 4) / 256, 256, 0, stream>>>((const float4*)x, (f16x4*)h16);
    trans_split_kernel<<<(2 * L_LAYERS * DIM * 2 * DIM) / 256, 256, 0, stream>>>(
        W1, W2, w1fh, w1fl, w2fh, w2fl);
    prep_params_kernel<<<5, 256, 0, stream>>>(b1, g1, be1, m1, v1, b2, go, bo, mo, vo,
                                              scale1, shift1, scale2, shift2);

    for (int i = 0; i < L_LAYERS; ++i) {
        aggregate_kernel<<<N_NODES / 4, 256, 0, stream>>>((const unsigned int*)h16,
                                                          rowp, col, eps + i, zfh, zfl);
        int last = (i == L_LAYERS - 1) ? 1 : 0;
        mlp_kernel<<<MTILES, 64, 0, stream>>>(zfh, zfl,
            w1fh + (size_t)i * 32768, w1fl + (size_t)i * 32768,
            w2fh + (size_t)i * 32768, w2fl + (size_t)i * 32768,
            scale1 + i * 256, shift1 + i * 256,
            scale2 + i * 128, shift2 + i * 128,
            last, h16, (float*)d_out);
    }
}